// Round 1
// baseline (421.509 us; speedup 1.0000x reference)
//
#include <hip/hip_runtime.h>

typedef unsigned short u16;
typedef __bf16 bf16x8 __attribute__((ext_vector_type(8)));
typedef float f32x4 __attribute__((ext_vector_type(4)));

#define MFMA16 __builtin_amdgcn_mfma_f32_16x16x32_bf16

constexpr int NB = 2, TS = 2048, HD = 1024, NH = 16, DH = 64;
constexpr float SCALE = 0.03125f;  // 1/sqrt(1024)

__device__ __forceinline__ u16 f2bf(float f) {
    union { float f; unsigned u; } v; v.f = f;
    unsigned r = v.u + 0x7FFFu + ((v.u >> 16) & 1u);  // RNE
    return (u16)(r >> 16);
}
__device__ __forceinline__ float bf2f(u16 h) {
    union { unsigned u; float f; } v; v.u = ((unsigned)h) << 16;
    return v.f;
}
__device__ __forceinline__ bf16x8 ldb8(const u16* p) {
    return *reinterpret_cast<const bf16x8*>(p);
}

// ---------------- weight transpose + fp32->bf16 -------------------------
// dst[n][k] = bf16(src[k][n]); 64x64 tiles via LDS. grid (16,16,4)
__global__ __launch_bounds__(256) void wtrans(
    const float* __restrict__ w0, const float* __restrict__ w1,
    const float* __restrict__ w2, const float* __restrict__ w3,
    u16* __restrict__ o0, u16* __restrict__ o1,
    u16* __restrict__ o2, u16* __restrict__ o3)
{
    const float* src; u16* dst;
    if (blockIdx.z == 0)      { src = w0; dst = o0; }
    else if (blockIdx.z == 1) { src = w1; dst = o1; }
    else if (blockIdx.z == 2) { src = w2; dst = o2; }
    else                      { src = w3; dst = o3; }
    __shared__ __align__(16) u16 tile[64 * 72];
    const int k0 = blockIdx.y * 64, n0 = blockIdx.x * 64;
    const int t = threadIdx.x, r = t >> 2, c0 = (t & 3) << 4;
#pragma unroll
    for (int j = 0; j < 4; ++j) {
        float4 v = *reinterpret_cast<const float4*>(&src[(size_t)(k0 + r) * HD + n0 + c0 + 4 * j]);
        tile[(c0 + 4 * j + 0) * 72 + r] = f2bf(v.x);
        tile[(c0 + 4 * j + 1) * 72 + r] = f2bf(v.y);
        tile[(c0 + 4 * j + 2) * 72 + r] = f2bf(v.z);
        tile[(c0 + 4 * j + 3) * 72 + r] = f2bf(v.w);
    }
    __syncthreads();
#pragma unroll
    for (int j = 0; j < 2; ++j)
        *reinterpret_cast<uint4*>(&dst[(size_t)(n0 + r) * HD + k0 + c0 + 8 * j]) =
            *reinterpret_cast<const uint4*>(&tile[r * 72 + c0 + 8 * j]);
}

// ---------------- GEMM: C[M,N] = A[M,K] @ BT[N,K]^T + bias --------------
// A: fp32 (converted in staging) or bf16. 128x128 tile, BK=32, 4 waves 2x2.
template <typename AT, typename OT>
__global__ __launch_bounds__(256) void gemm_bt(
    const AT* __restrict__ A, const u16* __restrict__ BT,
    const float* __restrict__ bias, OT* __restrict__ C,
    int M, int N, int K)
{
    __shared__ __align__(16) u16 As[128 * 40];  // +8 pad: 2-way LDS aliasing (free)
    __shared__ __align__(16) u16 Bs[128 * 40];
    const int m0 = blockIdx.y * 128, n0 = blockIdx.x * 128;
    const int t = threadIdx.x, wid = t >> 6, lane = t & 63;
    const int wm = wid >> 1, wn = wid & 1;
    const int lr = lane & 15, lk = (lane >> 4) << 3;
    const int sr = t >> 1, sc = (t & 1) << 4;
    f32x4 acc[4][4] = {};
    for (int k0 = 0; k0 < K; k0 += 32) {
        const AT* ap = A + (size_t)(m0 + sr) * K + k0 + sc;
        if constexpr (sizeof(AT) == 4) {
            u16 tmp[16];
#pragma unroll
            for (int j = 0; j < 4; ++j) {
                float4 v = *reinterpret_cast<const float4*>(reinterpret_cast<const float*>(ap) + 4 * j);
                tmp[4 * j + 0] = f2bf(v.x); tmp[4 * j + 1] = f2bf(v.y);
                tmp[4 * j + 2] = f2bf(v.z); tmp[4 * j + 3] = f2bf(v.w);
            }
            *reinterpret_cast<uint4*>(&As[sr * 40 + sc])     = *reinterpret_cast<const uint4*>(&tmp[0]);
            *reinterpret_cast<uint4*>(&As[sr * 40 + sc + 8]) = *reinterpret_cast<const uint4*>(&tmp[8]);
        } else {
            const u16* a16 = reinterpret_cast<const u16*>(ap);
            *reinterpret_cast<uint4*>(&As[sr * 40 + sc])     = *reinterpret_cast<const uint4*>(a16);
            *reinterpret_cast<uint4*>(&As[sr * 40 + sc + 8]) = *reinterpret_cast<const uint4*>(a16 + 8);
        }
        const u16* bp = BT + (size_t)(n0 + sr) * K + k0 + sc;
        *reinterpret_cast<uint4*>(&Bs[sr * 40 + sc])     = *reinterpret_cast<const uint4*>(bp);
        *reinterpret_cast<uint4*>(&Bs[sr * 40 + sc + 8]) = *reinterpret_cast<const uint4*>(bp + 8);
        __syncthreads();
        bf16x8 af[4], bfr[4];
#pragma unroll
        for (int i = 0; i < 4; ++i) af[i] = ldb8(&As[(wm * 64 + i * 16 + lr) * 40 + lk]);
#pragma unroll
        for (int j = 0; j < 4; ++j) bfr[j] = ldb8(&Bs[(wn * 64 + j * 16 + lr) * 40 + lk]);
#pragma unroll
        for (int i = 0; i < 4; ++i)
#pragma unroll
            for (int j = 0; j < 4; ++j)
                acc[i][j] = MFMA16(af[i], bfr[j], acc[i][j], 0, 0, 0);
        __syncthreads();
    }
    const int orow = (lane >> 4) << 2, ocol = lane & 15;  // C/D: col=lane&15, row=(lane>>4)*4+r
#pragma unroll
    for (int i = 0; i < 4; ++i) {
#pragma unroll
        for (int j = 0; j < 4; ++j) {
            int row = m0 + wm * 64 + i * 16 + orow;
            int col = n0 + wn * 64 + j * 16 + ocol;
            float b = bias[col];
#pragma unroll
            for (int r = 0; r < 4; ++r) {
                float v = acc[i][j][r] + b;
                if constexpr (sizeof(OT) == 4)
                    reinterpret_cast<float*>(C)[(size_t)(row + r) * N + col] = v;
                else
                    reinterpret_cast<u16*>(C)[(size_t)(row + r) * N + col] = f2bf(v);
            }
        }
    }
}

// ---------------- pass 1: Zinv[n,t,s] = 1 / sum_h exp(S[h,t,s]/32) ------
// grid (TS/64 s-tiles, TS/64 t-tiles, NB); 64x64 tile, 4 waves 2x2 quadrants
__global__ __launch_bounds__(256) void z_kernel(
    const u16* __restrict__ Qp, const u16* __restrict__ Kp, u16* __restrict__ Zinv)
{
    __shared__ __align__(16) u16 Qs[64 * 72], Ks[64 * 72];
    const int n = blockIdx.z;
    const int t0 = blockIdx.y * 64, s0 = blockIdx.x * 64;
    const int t = threadIdx.x, wid = t >> 6, lane = t & 63;
    const int wm = wid >> 1, wn = wid & 1;
    const int lr = lane & 15, lk = (lane >> 4) << 3;
    const int sr = t >> 2, sc = (t & 3) << 4;
    float zacc[2][2][4] = {};
    for (int h = 0; h < NH; ++h) {
        const u16* Qh = Qp + (size_t)(n * NH + h) * TS * DH;  // head = contiguous (2048x64)
        const u16* Kh = Kp + (size_t)(n * NH + h) * TS * DH;
        *reinterpret_cast<uint4*>(&Qs[sr * 72 + sc])     = *reinterpret_cast<const uint4*>(&Qh[(t0 + sr) * DH + sc]);
        *reinterpret_cast<uint4*>(&Qs[sr * 72 + sc + 8]) = *reinterpret_cast<const uint4*>(&Qh[(t0 + sr) * DH + sc + 8]);
        *reinterpret_cast<uint4*>(&Ks[sr * 72 + sc])     = *reinterpret_cast<const uint4*>(&Kh[(s0 + sr) * DH + sc]);
        *reinterpret_cast<uint4*>(&Ks[sr * 72 + sc + 8]) = *reinterpret_cast<const uint4*>(&Kh[(s0 + sr) * DH + sc + 8]);
        __syncthreads();
        f32x4 sacc[2][2] = {};
#pragma unroll
        for (int kk = 0; kk < 2; ++kk) {
            bf16x8 qa[2], kb[2];
#pragma unroll
            for (int i = 0; i < 2; ++i) qa[i] = ldb8(&Qs[(wm * 32 + i * 16 + lr) * 72 + kk * 32 + lk]);
#pragma unroll
            for (int j = 0; j < 2; ++j) kb[j] = ldb8(&Ks[(wn * 32 + j * 16 + lr) * 72 + kk * 32 + lk]);
#pragma unroll
            for (int i = 0; i < 2; ++i)
#pragma unroll
                for (int j = 0; j < 2; ++j)
                    sacc[i][j] = MFMA16(qa[i], kb[j], sacc[i][j], 0, 0, 0);
        }
#pragma unroll
        for (int i = 0; i < 2; ++i)
#pragma unroll
            for (int j = 0; j < 2; ++j)
#pragma unroll
                for (int r = 0; r < 4; ++r)
                    zacc[i][j][r] += __expf(sacc[i][j][r] * SCALE);
        __syncthreads();
    }
    const int orow = (lane >> 4) << 2, ocol = lane & 15;
#pragma unroll
    for (int i = 0; i < 2; ++i)
#pragma unroll
        for (int j = 0; j < 2; ++j)
#pragma unroll
            for (int r = 0; r < 4; ++r) {
                int tt = t0 + wm * 32 + i * 16 + orow + r;
                int ss = s0 + wn * 32 + j * 16 + ocol;
                Zinv[(size_t)(n * TS + tt) * TS + ss] = f2bf(1.0f / zacc[i][j][r]);
            }
}

// ---------------- pass 2: out2[h] = (exp(S/32) * Zinv) @ V[h] -----------
// grid (TS/64 t-tiles, NH, NB); s-loop over 64-tiles
__global__ __launch_bounds__(256) void attn_kernel(
    const u16* __restrict__ Qp, const u16* __restrict__ Kp, const u16* __restrict__ Vp,
    const u16* __restrict__ Zinv, u16* __restrict__ out2)
{
    __shared__ __align__(16) u16 Qs[64 * 72], Ks[64 * 72], VTs[64 * 72], Ps[64 * 72], Zs[64 * 72];
    const int tb = blockIdx.x * 64, h = blockIdx.y, n = blockIdx.z;
    const int t = threadIdx.x, wid = t >> 6, lane = t & 63;
    const int wm = wid >> 1, wn = wid & 1;
    const int lr = lane & 15, lk = (lane >> 4) << 3;
    const int sr = t >> 2, sc = (t & 3) << 4;
    const size_t base = (size_t)(n * NH + h) * TS * DH;
    const u16* Qh = Qp + base; const u16* Kh = Kp + base; const u16* Vh = Vp + base;
    // stage Q once (sync'd by first in-loop barrier)
    *reinterpret_cast<uint4*>(&Qs[sr * 72 + sc])     = *reinterpret_cast<const uint4*>(&Qh[(tb + sr) * DH + sc]);
    *reinterpret_cast<uint4*>(&Qs[sr * 72 + sc + 8]) = *reinterpret_cast<const uint4*>(&Qh[(tb + sr) * DH + sc + 8]);
    const int vs = t & 63, vd0 = (t >> 6) << 4;
    const int orow = (lane >> 4) << 2, ocol = lane & 15;
    f32x4 oacc[2][2] = {};
    for (int s0 = 0; s0 < TS; s0 += 64) {
        *reinterpret_cast<uint4*>(&Ks[sr * 72 + sc])     = *reinterpret_cast<const uint4*>(&Kh[(s0 + sr) * DH + sc]);
        *reinterpret_cast<uint4*>(&Ks[sr * 72 + sc + 8]) = *reinterpret_cast<const uint4*>(&Kh[(s0 + sr) * DH + sc + 8]);
        *reinterpret_cast<uint4*>(&Zs[sr * 72 + sc])     = *reinterpret_cast<const uint4*>(&Zinv[(size_t)(n * TS + tb + sr) * TS + s0 + sc]);
        *reinterpret_cast<uint4*>(&Zs[sr * 72 + sc + 8]) = *reinterpret_cast<const uint4*>(&Zinv[(size_t)(n * TS + tb + sr) * TS + s0 + sc + 8]);
        {   // V staged transposed: VTs[d][s] so B-fragment (k=s contiguous) reads 16B rows
            uint4 u0 = *reinterpret_cast<const uint4*>(&Vh[(s0 + vs) * DH + vd0]);
            uint4 u1 = *reinterpret_cast<const uint4*>(&Vh[(s0 + vs) * DH + vd0 + 8]);
            u16 tmp[16];
            *reinterpret_cast<uint4*>(&tmp[0]) = u0;
            *reinterpret_cast<uint4*>(&tmp[8]) = u1;
#pragma unroll
            for (int ii = 0; ii < 16; ++ii) VTs[(vd0 + ii) * 72 + vs] = tmp[ii];
        }
        __syncthreads();
        f32x4 sacc[2][2] = {};
#pragma unroll
        for (int kk = 0; kk < 2; ++kk) {
            bf16x8 qa[2], kb[2];
#pragma unroll
            for (int i = 0; i < 2; ++i) qa[i] = ldb8(&Qs[(wm * 32 + i * 16 + lr) * 72 + kk * 32 + lk]);
#pragma unroll
            for (int j = 0; j < 2; ++j) kb[j] = ldb8(&Ks[(wn * 32 + j * 16 + lr) * 72 + kk * 32 + lk]);
#pragma unroll
            for (int i = 0; i < 2; ++i)
#pragma unroll
                for (int j = 0; j < 2; ++j)
                    sacc[i][j] = MFMA16(qa[i], kb[j], sacc[i][j], 0, 0, 0);
        }
#pragma unroll
        for (int i = 0; i < 2; ++i)
#pragma unroll
            for (int j = 0; j < 2; ++j)
#pragma unroll
                for (int r = 0; r < 4; ++r) {
                    int tt = wm * 32 + i * 16 + orow + r;
                    int ss = wn * 32 + j * 16 + ocol;
                    float zi = bf2f(Zs[tt * 72 + ss]);
                    Ps[tt * 72 + ss] = f2bf(__expf(sacc[i][j][r] * SCALE) * zi);
                }
        __syncthreads();
#pragma unroll
        for (int kk = 0; kk < 2; ++kk) {
            bf16x8 pa[2], vb[2];
#pragma unroll
            for (int i = 0; i < 2; ++i) pa[i] = ldb8(&Ps[(wm * 32 + i * 16 + lr) * 72 + kk * 32 + lk]);
#pragma unroll
            for (int j = 0; j < 2; ++j) vb[j] = ldb8(&VTs[(wn * 32 + j * 16 + lr) * 72 + kk * 32 + lk]);
#pragma unroll
            for (int i = 0; i < 2; ++i)
#pragma unroll
                for (int j = 0; j < 2; ++j)
                    oacc[i][j] = MFMA16(pa[i], vb[j], oacc[i][j], 0, 0, 0);
        }
        __syncthreads();
    }
#pragma unroll
    for (int i = 0; i < 2; ++i)
#pragma unroll
        for (int j = 0; j < 2; ++j)
#pragma unroll
            for (int r = 0; r < 4; ++r) {
                int tt = tb + wm * 32 + i * 16 + orow + r;
                int dd = wn * 32 + j * 16 + ocol;
                out2[base + (size_t)tt * DH + dd] = f2bf(oacc[i][j][r]);
            }
}

extern "C" void kernel_launch(void* const* d_in, const int* in_sizes, int n_in,
                              void* d_out, int out_size, void* d_ws, size_t ws_size,
                              hipStream_t stream)
{
    const float* q  = (const float*)d_in[0];
    const float* k  = (const float*)d_in[1];
    const float* v  = (const float*)d_in[2];
    const float* Wq = (const float*)d_in[3];
    const float* bq = (const float*)d_in[4];
    const float* Wk = (const float*)d_in[5];
    const float* bk = (const float*)d_in[6];
    const float* Wv = (const float*)d_in[7];
    const float* bv = (const float*)d_in[8];
    const float* Wo = (const float*)d_in[9];
    const float* bo = (const float*)d_in[10];
    float* out = (float*)d_out;

    // ws layout (u16 elements): 4 x WT (1M each), Qp/Kp/Vp/out2 (4M each), Zinv (8M)
    u16* ws  = (u16*)d_ws;
    u16* wqT = ws;
    u16* wkT = ws + 1 * 1048576;
    u16* wvT = ws + 2 * 1048576;
    u16* woT = ws + 3 * 1048576;
    u16* Qp  = ws + 4 * 1048576;
    u16* Kp  = Qp + 4194304;
    u16* Vp  = Kp + 4194304;
    u16* o2  = Vp + 4194304;
    u16* Zi  = o2 + 4194304;   // 2*2048*2048 u16 = 16 MB

    wtrans<<<dim3(16, 16, 4), 256, 0, stream>>>(Wq, Wk, Wv, Wo, wqT, wkT, wvT, woT);
    gemm_bt<float, u16><<<dim3(8, 32), 256, 0, stream>>>(q, wqT, bq, Qp, NB * TS, HD, HD);
    gemm_bt<float, u16><<<dim3(8, 32), 256, 0, stream>>>(k, wkT, bk, Kp, NB * TS, HD, HD);
    gemm_bt<float, u16><<<dim3(8, 32), 256, 0, stream>>>(v, wvT, bv, Vp, NB * TS, HD, HD);
    z_kernel<<<dim3(TS / 64, TS / 64, NB), 256, 0, stream>>>(Qp, Kp, Zi);
    attn_kernel<<<dim3(TS / 64, NH, NB), 256, 0, stream>>>(Qp, Kp, Vp, Zi, o2);
    gemm_bt<u16, float><<<dim3(8, 32), 256, 0, stream>>>(o2, woT, bo, out, NB * TS, HD, HD);
}

// Round 3
// 332.744 us; speedup vs baseline: 1.2668x; 1.2668x over previous
//
#include <hip/hip_runtime.h>

typedef unsigned short u16;
typedef __bf16 bf16x8 __attribute__((ext_vector_type(8)));
typedef float f32x4 __attribute__((ext_vector_type(4)));

#define MFMA16 __builtin_amdgcn_mfma_f32_16x16x32_bf16

constexpr int NB = 2, TS = 2048, HD = 1024, NH = 16, DH = 64;
constexpr float SCALE = 0.03125f;  // 1/sqrt(1024)

__device__ __forceinline__ u16 f2bf(float f) {
    union { float f; unsigned u; } v; v.f = f;
    unsigned r = v.u + 0x7FFFu + ((v.u >> 16) & 1u);  // RNE
    return (u16)(r >> 16);
}
__device__ __forceinline__ float bf2f(u16 h) {
    union { unsigned u; float f; } v; v.u = ((unsigned)h) << 16;
    return v.f;
}
__device__ __forceinline__ bf16x8 ldb8(const u16* p) {
    return *reinterpret_cast<const bf16x8*>(p);
}
// async global->LDS, 16B per lane; LDS dest = wave-uniform base + lane*16
__device__ __forceinline__ void glds16(const u16* g, u16* l) {
    __builtin_amdgcn_global_load_lds(
        (const __attribute__((address_space(1))) unsigned int*)g,
        (__attribute__((address_space(3))) unsigned int*)l, 16, 0, 0);
}

// ---------------- fp32 -> bf16 bulk convert (q,k,v) ---------------------
// 4,194,304 elements each; 256 thr x 8 elem => 2048 blocks. (4096 was the
// round-2 OOB crash.)
__global__ __launch_bounds__(256) void to_bf16(
    const float* __restrict__ a0, const float* __restrict__ a1, const float* __restrict__ a2,
    u16* __restrict__ o0, u16* __restrict__ o1, u16* __restrict__ o2)
{
    const float* s; u16* d;
    if (blockIdx.y == 0)      { s = a0; d = o0; }
    else if (blockIdx.y == 1) { s = a1; d = o1; }
    else                      { s = a2; d = o2; }
    size_t i = ((size_t)blockIdx.x * 256 + threadIdx.x) * 8;
    float4 v0 = *reinterpret_cast<const float4*>(s + i);
    float4 v1 = *reinterpret_cast<const float4*>(s + i + 4);
    u16 t[8] = { f2bf(v0.x), f2bf(v0.y), f2bf(v0.z), f2bf(v0.w),
                 f2bf(v1.x), f2bf(v1.y), f2bf(v1.z), f2bf(v1.w) };
    *reinterpret_cast<uint4*>(d + i) = *reinterpret_cast<const uint4*>(t);
}

// ---------------- weight transpose + fp32->bf16 -------------------------
__global__ __launch_bounds__(256) void wtrans(
    const float* __restrict__ w0, const float* __restrict__ w1,
    const float* __restrict__ w2, const float* __restrict__ w3,
    u16* __restrict__ o0, u16* __restrict__ o1,
    u16* __restrict__ o2, u16* __restrict__ o3)
{
    const float* src; u16* dst;
    if (blockIdx.z == 0)      { src = w0; dst = o0; }
    else if (blockIdx.z == 1) { src = w1; dst = o1; }
    else if (blockIdx.z == 2) { src = w2; dst = o2; }
    else                      { src = w3; dst = o3; }
    __shared__ __align__(16) u16 tile[64 * 72];
    const int k0 = blockIdx.y * 64, n0 = blockIdx.x * 64;
    const int t = threadIdx.x, r = t >> 2, c0 = (t & 3) << 4;
#pragma unroll
    for (int j = 0; j < 4; ++j) {
        float4 v = *reinterpret_cast<const float4*>(&src[(size_t)(k0 + r) * HD + n0 + c0 + 4 * j]);
        tile[(c0 + 4 * j + 0) * 72 + r] = f2bf(v.x);
        tile[(c0 + 4 * j + 1) * 72 + r] = f2bf(v.y);
        tile[(c0 + 4 * j + 2) * 72 + r] = f2bf(v.z);
        tile[(c0 + 4 * j + 3) * 72 + r] = f2bf(v.w);
    }
    __syncthreads();
#pragma unroll
    for (int j = 0; j < 2; ++j)
        *reinterpret_cast<uint4*>(&dst[(size_t)(n0 + r) * HD + k0 + c0 + 8 * j]) =
            *reinterpret_cast<const uint4*>(&tile[r * 72 + c0 + 8 * j]);
}

// -------- GEMM: C[M,N] = A[M,K](bf16) @ BT[N,K]^T + bias ----------------
// 64x128 tile, BK=32, 4 waves (2x2), global_load_lds staging, unpadded LDS.
template <typename OT>
__global__ __launch_bounds__(256) void gemm_bt(
    const u16* __restrict__ A, const u16* __restrict__ BT,
    const float* __restrict__ bias, OT* __restrict__ C,
    int M, int N, int K)
{
    __shared__ __align__(16) u16 As[64 * 32];
    __shared__ __align__(16) u16 Bs[128 * 32];
    const int m0 = blockIdx.y * 64, n0 = blockIdx.x * 128;
    const int tid = threadIdx.x, wid = tid >> 6, lane = tid & 63;
    const int q = lane >> 4, c = lane & 15;
    const int wm = wid >> 1, wn = wid & 1;
    const int arow = tid >> 2, acol = (tid & 3) << 3;
    f32x4 acc[2][4] = {};
    for (int k0 = 0; k0 < K; k0 += 32) {
        glds16(&A[(size_t)(m0 + arow) * K + k0 + acol], &As[tid * 8]);
        glds16(&BT[(size_t)(n0 + arow) * K + k0 + acol], &Bs[tid * 8]);
        glds16(&BT[(size_t)(n0 + 64 + arow) * K + k0 + acol], &Bs[2048 + tid * 8]);
        __syncthreads();
        bf16x8 af[2], bf[4];
#pragma unroll
        for (int jm = 0; jm < 2; ++jm) af[jm] = ldb8(&As[(wm * 32 + jm * 16 + c) * 32 + q * 8]);
#pragma unroll
        for (int jn = 0; jn < 4; ++jn) bf[jn] = ldb8(&Bs[(wn * 64 + jn * 16 + c) * 32 + q * 8]);
#pragma unroll
        for (int jm = 0; jm < 2; ++jm)
#pragma unroll
            for (int jn = 0; jn < 4; ++jn)
                acc[jm][jn] = MFMA16(af[jm], bf[jn], acc[jm][jn], 0, 0, 0);
        __syncthreads();
    }
#pragma unroll
    for (int jm = 0; jm < 2; ++jm)
#pragma unroll
        for (int jn = 0; jn < 4; ++jn) {
            int row = m0 + wm * 32 + jm * 16 + q * 4;
            int col = n0 + wn * 64 + jn * 16 + c;
            float b = bias[col];
#pragma unroll
            for (int r = 0; r < 4; ++r) {
                float v = acc[jm][jn][r] + b;
                if constexpr (sizeof(OT) == 4)
                    reinterpret_cast<float*>(C)[(size_t)(row + r) * N + col] = v;
                else
                    reinterpret_cast<u16*>(C)[(size_t)(row + r) * N + col] = f2bf(v);
            }
        }
}

// ---------------- V transpose per head: VT[nh][d][t] --------------------
__global__ __launch_bounds__(256) void vtrans(const u16* __restrict__ V, u16* __restrict__ VT)
{
    __shared__ __align__(16) u16 tile[64 * 72];
    const int nh = blockIdx.y, t0 = blockIdx.x * 64;
    const u16* src = V + (size_t)nh * TS * DH;
    u16* dst = VT + (size_t)nh * DH * TS;
    const int t = threadIdx.x, r = t >> 2, c0 = (t & 3) << 4;
    *reinterpret_cast<uint4*>(&tile[r * 72 + c0]) =
        *reinterpret_cast<const uint4*>(&src[(size_t)(t0 + r) * DH + c0]);
    *reinterpret_cast<uint4*>(&tile[r * 72 + c0 + 8]) =
        *reinterpret_cast<const uint4*>(&src[(size_t)(t0 + r) * DH + c0 + 8]);
    __syncthreads();
    const int d = t >> 2, tc = (t & 3) << 4;
    u16 tmp[16];
#pragma unroll
    for (int j = 0; j < 16; ++j) tmp[j] = tile[(tc + j) * 72 + d];
    *reinterpret_cast<uint4*>(&dst[(size_t)d * TS + t0 + tc]) = *reinterpret_cast<const uint4*>(&tmp[0]);
    *reinterpret_cast<uint4*>(&dst[(size_t)d * TS + t0 + tc + 8]) = *reinterpret_cast<const uint4*>(&tmp[8]);
}

// -------- pass 1: Zfrag = 1/sum_h exp(S/32), stored in frag order -------
// grid (32 sb, 16 tb, 2 n); tile t=128 x s=64; 4 waves = t-quarters.
__global__ __launch_bounds__(256) void z_kernel(
    const u16* __restrict__ Qp, const u16* __restrict__ Kp, u16* __restrict__ Zf)
{
    __shared__ __align__(16) u16 Ks[64 * 64];
    const int sb = blockIdx.x, tb = blockIdx.y, n = blockIdx.z;
    const int s0 = sb * 64, t0 = tb * 128;
    const int tid = threadIdx.x, wid = tid >> 6, lane = tid & 63;
    const int q = lane >> 4, c = lane & 15;
    const int krow = tid >> 3, kch = tid & 7;
    float zacc[2][4][4] = {};
    for (int h = 0; h < NH; ++h) {
        const u16* Qh = Qp + (size_t)(n * NH + h) * TS * DH;
        const u16* Kh = Kp + (size_t)(n * NH + h) * TS * DH;
        glds16(&Kh[(size_t)(s0 + krow) * DH + ((kch ^ (krow & 7)) << 3)], &Ks[tid * 8]);
        glds16(&Kh[(size_t)(s0 + 32 + krow) * DH + ((kch ^ (krow & 7)) << 3)], &Ks[2048 + tid * 8]);
        __syncthreads();
        bf16x8 qa[2][2], kb[4][2];
#pragma unroll
        for (int jm = 0; jm < 2; ++jm)
#pragma unroll
            for (int kf = 0; kf < 2; ++kf)
                qa[jm][kf] = ldb8(&Qh[(size_t)(t0 + wid * 32 + jm * 16 + c) * DH + kf * 32 + q * 8]);
#pragma unroll
        for (int i = 0; i < 4; ++i)
#pragma unroll
            for (int kf = 0; kf < 2; ++kf)
                kb[i][kf] = ldb8(&Ks[(i * 16 + c) * 64 + (((kf * 4 + q) ^ (c & 7)) << 3)]);
        f32x4 s_[2][4] = {};
#pragma unroll
        for (int kf = 0; kf < 2; ++kf)
#pragma unroll
            for (int jm = 0; jm < 2; ++jm)
#pragma unroll
                for (int i = 0; i < 4; ++i)
                    s_[jm][i] = MFMA16(qa[jm][kf], kb[i][kf], s_[jm][i], 0, 0, 0);
#pragma unroll
        for (int jm = 0; jm < 2; ++jm)
#pragma unroll
            for (int i = 0; i < 4; ++i)
#pragma unroll
                for (int r = 0; r < 4; ++r)
                    zacc[jm][i][r] += __expf(s_[jm][i][r] * SCALE);
        __syncthreads();
    }
    size_t chunk = ((size_t)((n * 32 + sb) * 16 + tb)) * 8192 + wid * 2048 + lane * 32;
#pragma unroll
    for (int jm = 0; jm < 2; ++jm) {
        u16 w_[16];
#pragma unroll
        for (int i = 0; i < 4; ++i)
#pragma unroll
            for (int r = 0; r < 4; ++r)
                w_[i * 4 + r] = f2bf(1.0f / zacc[jm][i][r]);
        *reinterpret_cast<uint4*>(&Zf[chunk + jm * 16])     = *reinterpret_cast<const uint4*>(&w_[0]);
        *reinterpret_cast<uint4*>(&Zf[chunk + jm * 16 + 8]) = *reinterpret_cast<const uint4*>(&w_[8]);
    }
}

// -------- pass 2: out2[h] = (exp(S/32) * Zinv) @ V[h] -------------------
// grid (16 tb, 16 h, 2 n); t-tile 128 (4 waves x 32t), s-loop 64.
__global__ __launch_bounds__(256) void attn_kernel(
    const u16* __restrict__ Qp, const u16* __restrict__ Kp, const u16* __restrict__ VT,
    const u16* __restrict__ Zf, u16* __restrict__ o2)
{
    __shared__ __align__(16) u16 Ks[64 * 64];
    __shared__ __align__(16) u16 Vs[64 * 64];
    __shared__ __align__(16) u16 Ps[128 * 72];   // per-wave-private t-quarters
    const int tb = blockIdx.x, h = blockIdx.y, n = blockIdx.z;
    const int t0 = tb * 128;
    const int tid = threadIdx.x, wid = tid >> 6, lane = tid & 63;
    const int q = lane >> 4, c = lane & 15;
    const int krow = tid >> 3, kch = tid & 7;
    const size_t base = (size_t)(n * NH + h) * TS * DH;
    const u16* Qh = Qp + base; const u16* Kh = Kp + base; const u16* VTh = VT + base;
    bf16x8 qa[2][2];
#pragma unroll
    for (int jm = 0; jm < 2; ++jm)
#pragma unroll
        for (int kf = 0; kf < 2; ++kf)
            qa[jm][kf] = ldb8(&Qh[(size_t)(t0 + wid * 32 + jm * 16 + c) * DH + kf * 32 + q * 8]);
    f32x4 oacc[2][4] = {};
    for (int sb = 0; sb < 32; ++sb) {
        const int s0 = sb * 64;
        glds16(&Kh[(size_t)(s0 + krow) * DH + ((kch ^ (krow & 7)) << 3)], &Ks[tid * 8]);
        glds16(&Kh[(size_t)(s0 + 32 + krow) * DH + ((kch ^ (krow & 7)) << 3)], &Ks[2048 + tid * 8]);
        glds16(&VTh[(size_t)krow * TS + s0 + ((kch ^ (krow & 7)) << 3)], &Vs[tid * 8]);
        glds16(&VTh[(size_t)(32 + krow) * TS + s0 + ((kch ^ (krow & 7)) << 3)], &Vs[2048 + tid * 8]);
        __syncthreads();
        bf16x8 kb[4][2];
#pragma unroll
        for (int i = 0; i < 4; ++i)
#pragma unroll
            for (int kf = 0; kf < 2; ++kf)
                kb[i][kf] = ldb8(&Ks[(i * 16 + c) * 64 + (((kf * 4 + q) ^ (c & 7)) << 3)]);
        f32x4 s_[2][4] = {};
#pragma unroll
        for (int kf = 0; kf < 2; ++kf)
#pragma unroll
            for (int jm = 0; jm < 2; ++jm)
#pragma unroll
                for (int i = 0; i < 4; ++i)
                    s_[jm][i] = MFMA16(qa[jm][kf], kb[i][kf], s_[jm][i], 0, 0, 0);
        // Zinv in frag order: 4 coalesced 16B loads per lane
        size_t chunk = ((size_t)((n * 32 + sb) * 16 + tb)) * 8192 + wid * 2048 + lane * 32;
        u16 zl[32];
        *reinterpret_cast<uint4*>(&zl[0])  = *reinterpret_cast<const uint4*>(&Zf[chunk]);
        *reinterpret_cast<uint4*>(&zl[8])  = *reinterpret_cast<const uint4*>(&Zf[chunk + 8]);
        *reinterpret_cast<uint4*>(&zl[16]) = *reinterpret_cast<const uint4*>(&Zf[chunk + 16]);
        *reinterpret_cast<uint4*>(&zl[24]) = *reinterpret_cast<const uint4*>(&Zf[chunk + 24]);
#pragma unroll
        for (int jm = 0; jm < 2; ++jm)
#pragma unroll
            for (int i = 0; i < 4; ++i)
#pragma unroll
                for (int r = 0; r < 4; ++r) {
                    float p = __expf(s_[jm][i][r] * SCALE) * bf2f(zl[jm * 16 + i * 4 + r]);
                    Ps[(wid * 32 + jm * 16 + q * 4 + r) * 72 + i * 16 + c] = f2bf(p);
                }
        // wave-private region: no barrier needed (in-wave LDS dep via lgkmcnt)
        bf16x8 pa[2][2], vb[4][2];
#pragma unroll
        for (int jm = 0; jm < 2; ++jm)
#pragma unroll
            for (int kf = 0; kf < 2; ++kf)
                pa[jm][kf] = ldb8(&Ps[(wid * 32 + jm * 16 + c) * 72 + kf * 32 + q * 8]);
#pragma unroll
        for (int dn = 0; dn < 4; ++dn)
#pragma unroll
            for (int kf = 0; kf < 2; ++kf)
                vb[dn][kf] = ldb8(&Vs[(dn * 16 + c) * 64 + (((kf * 4 + q) ^ (c & 7)) << 3)]);
#pragma unroll
        for (int kf = 0; kf < 2; ++kf)
#pragma unroll
            for (int jm = 0; jm < 2; ++jm)
#pragma unroll
                for (int dn = 0; dn < 4; ++dn)
                    oacc[jm][dn] = MFMA16(pa[jm][kf], vb[dn][kf], oacc[jm][dn], 0, 0, 0);
        __syncthreads();
    }
#pragma unroll
    for (int jm = 0; jm < 2; ++jm)
#pragma unroll
        for (int dn = 0; dn < 4; ++dn)
#pragma unroll
            for (int r = 0; r < 4; ++r)
                o2[base + (size_t)(t0 + wid * 32 + jm * 16 + q * 4 + r) * DH + dn * 16 + c] =
                    f2bf(oacc[jm][dn][r]);
}

extern "C" void kernel_launch(void* const* d_in, const int* in_sizes, int n_in,
                              void* d_out, int out_size, void* d_ws, size_t ws_size,
                              hipStream_t stream)
{
    const float* q  = (const float*)d_in[0];
    const float* k  = (const float*)d_in[1];
    const float* v  = (const float*)d_in[2];
    const float* Wq = (const float*)d_in[3];
    const float* bq = (const float*)d_in[4];
    const float* Wk = (const float*)d_in[5];
    const float* bk = (const float*)d_in[6];
    const float* Wv = (const float*)d_in[7];
    const float* bv = (const float*)d_in[8];
    const float* Wo = (const float*)d_in[9];
    const float* bo = (const float*)d_in[10];
    float* out = (float*)d_out;

    // ws layout (u16 elems), 56 MiB total (round-1-proven footprint), with
    // stream-ordered slot reuse:
    //   S1: qb -> Kp      S2: kb -> Vp -> o2     S3: vb -> VTb
    //   S4: Qp            S5: Zf (16 MiB)
    u16* ws  = (u16*)d_ws;
    u16* wqT = ws + 0 * 1048576;
    u16* wkT = ws + 1 * 1048576;
    u16* wvT = ws + 2 * 1048576;
    u16* woT = ws + 3 * 1048576;
    u16* S1  = ws + 4194304;
    u16* S2  = S1 + 4194304;
    u16* S3  = S2 + 4194304;
    u16* S4  = S3 + 4194304;
    u16* S5  = S4 + 4194304;
    u16* qb = S1, * kb = S2, * vb = S3;
    u16* Qp = S4, * Kp = S1, * Vp = S2;
    u16* VTb = S3, * Zf = S5, * o2 = S2;

    to_bf16<<<dim3(2048, 3), 256, 0, stream>>>(q, k, v, qb, kb, vb);
    wtrans<<<dim3(16, 16, 4), 256, 0, stream>>>(Wq, Wk, Wv, Wo, wqT, wkT, wvT, woT);
    gemm_bt<u16><<<dim3(8, 64), 256, 0, stream>>>(qb, wqT, bq, Qp, NB * TS, HD, HD);
    gemm_bt<u16><<<dim3(8, 64), 256, 0, stream>>>(kb, wkT, bk, Kp, NB * TS, HD, HD);
    gemm_bt<u16><<<dim3(8, 64), 256, 0, stream>>>(vb, wvT, bv, Vp, NB * TS, HD, HD);
    vtrans<<<dim3(32, 32), 256, 0, stream>>>(Vp, VTb);
    z_kernel<<<dim3(32, 16, 2), 256, 0, stream>>>(Qp, Kp, Zf);
    attn_kernel<<<dim3(16, 16, 2), 256, 0, stream>>>(Qp, Kp, VTb, Zf, o2);
    gemm_bt<float><<<dim3(8, 64), 256, 0, stream>>>(o2, woT, bo, out, NB * TS, HD, HD);
}

// Round 4
// 324.014 us; speedup vs baseline: 1.3009x; 1.0269x over previous
//
#include <hip/hip_runtime.h>

typedef unsigned short u16;
typedef __bf16 bf16x8 __attribute__((ext_vector_type(8)));
typedef float f32x4 __attribute__((ext_vector_type(4)));

#define MFMA16 __builtin_amdgcn_mfma_f32_16x16x32_bf16

constexpr int NB = 2, TS = 2048, HD = 1024, NH = 16, DH = 64;
constexpr float SCALE = 0.03125f;  // 1/sqrt(1024)

__device__ __forceinline__ u16 f2bf(float f) {
    union { float f; unsigned u; } v; v.f = f;
    unsigned r = v.u + 0x7FFFu + ((v.u >> 16) & 1u);  // RNE
    return (u16)(r >> 16);
}
__device__ __forceinline__ float bf2f(u16 h) {
    union { unsigned u; float f; } v; v.u = ((unsigned)h) << 16;
    return v.f;
}
__device__ __forceinline__ bf16x8 ldb8(const u16* p) {
    return *reinterpret_cast<const bf16x8*>(p);
}
__device__ __forceinline__ void glds16(const u16* g, u16* l) {
    __builtin_amdgcn_global_load_lds(
        (const __attribute__((address_space(1))) unsigned int*)g,
        (__attribute__((address_space(3))) unsigned int*)l, 16, 0, 0);
}

#if defined(__has_builtin)
#  if __has_builtin(__builtin_amdgcn_cvt_pk_bf16_f32)
#    define HAVE_PKBF16 1
#  endif
#endif
#ifndef HAVE_PKBF16
#  define HAVE_PKBF16 0
#endif
// pack 2 fp32 -> 2 bf16 in a u32 (lo = a, hi = b)
__device__ __forceinline__ unsigned pk2(float a, float b) {
#if HAVE_PKBF16
    typedef __bf16 bf16x2 __attribute__((ext_vector_type(2)));
    bf16x2 r = __builtin_amdgcn_cvt_pk_bf16_f32(a, b);
    return __builtin_bit_cast(unsigned, r);
#else
    return (unsigned)f2bf(a) | ((unsigned)f2bf(b) << 16);
#endif
}

// ---------------- fp32 -> bf16 bulk convert (q,k,v) ---------------------
// 4,194,304 elems each; 256 thr x 8 => 2048 blocks.
__global__ __launch_bounds__(256) void to_bf16(
    const float* __restrict__ a0, const float* __restrict__ a1, const float* __restrict__ a2,
    u16* __restrict__ o0, u16* __restrict__ o1, u16* __restrict__ o2)
{
    const float* s; u16* d;
    if (blockIdx.y == 0)      { s = a0; d = o0; }
    else if (blockIdx.y == 1) { s = a1; d = o1; }
    else                      { s = a2; d = o2; }
    size_t i = ((size_t)blockIdx.x * 256 + threadIdx.x) * 8;
    float4 v0 = *reinterpret_cast<const float4*>(s + i);
    float4 v1 = *reinterpret_cast<const float4*>(s + i + 4);
    uint4 w = { pk2(v0.x, v0.y), pk2(v0.z, v0.w), pk2(v1.x, v1.y), pk2(v1.z, v1.w) };
    *reinterpret_cast<uint4*>(d + i) = w;
}

// ---------------- weight transpose + fp32->bf16 -------------------------
__global__ __launch_bounds__(256) void wtrans(
    const float* __restrict__ w0, const float* __restrict__ w1,
    const float* __restrict__ w2, const float* __restrict__ w3,
    u16* __restrict__ o0, u16* __restrict__ o1,
    u16* __restrict__ o2, u16* __restrict__ o3)
{
    const float* src; u16* dst;
    if (blockIdx.z == 0)      { src = w0; dst = o0; }
    else if (blockIdx.z == 1) { src = w1; dst = o1; }
    else if (blockIdx.z == 2) { src = w2; dst = o2; }
    else                      { src = w3; dst = o3; }
    __shared__ __align__(16) u16 tile[64 * 72];
    const int k0 = blockIdx.y * 64, n0 = blockIdx.x * 64;
    const int t = threadIdx.x, r = t >> 2, c0 = (t & 3) << 4;
#pragma unroll
    for (int j = 0; j < 4; ++j) {
        float4 v = *reinterpret_cast<const float4*>(&src[(size_t)(k0 + r) * HD + n0 + c0 + 4 * j]);
        tile[(c0 + 4 * j + 0) * 72 + r] = f2bf(v.x);
        tile[(c0 + 4 * j + 1) * 72 + r] = f2bf(v.y);
        tile[(c0 + 4 * j + 2) * 72 + r] = f2bf(v.z);
        tile[(c0 + 4 * j + 3) * 72 + r] = f2bf(v.w);
    }
    __syncthreads();
#pragma unroll
    for (int j = 0; j < 2; ++j)
        *reinterpret_cast<uint4*>(&dst[(size_t)(n0 + r) * HD + k0 + c0 + 8 * j]) =
            *reinterpret_cast<const uint4*>(&tile[r * 72 + c0 + 8 * j]);
}

// -------- merged Q/K/V projection GEMM, 128x128 tile (m97 structure) ----
// C[M,N] = A[M,K] @ BT[N,K]^T + bias, bf16 out. grid (8, 32, 3).
__global__ __launch_bounds__(256) void gemm_qkv(
    const u16* __restrict__ A0, const u16* __restrict__ A1, const u16* __restrict__ A2,
    const u16* __restrict__ B0, const u16* __restrict__ B1, const u16* __restrict__ B2,
    const float* __restrict__ c0, const float* __restrict__ c1, const float* __restrict__ c2,
    u16* __restrict__ C0, u16* __restrict__ C1, u16* __restrict__ C2)
{
    const u16 *A, *BT; const float* bias; u16* C;
    if (blockIdx.z == 0)      { A = A0; BT = B0; bias = c0; C = C0; }
    else if (blockIdx.z == 1) { A = A1; BT = B1; bias = c1; C = C1; }
    else                      { A = A2; BT = B2; bias = c2; C = C2; }
    constexpr int M = NB * TS, N = HD, K = HD;
    __shared__ __align__(16) u16 As[128 * 32];
    __shared__ __align__(16) u16 Bs[128 * 32];
    const int m0 = blockIdx.y * 128, n0 = blockIdx.x * 128;
    const int tid = threadIdx.x, wid = tid >> 6, lane = tid & 63;
    const int q = lane >> 4, c = lane & 15;
    const int wm = wid >> 1, wn = wid & 1;
    const int srow = tid >> 2, scol = (tid & 3) << 3;
    (void)M;
    f32x4 acc[4][4] = {};
    for (int k0 = 0; k0 < K; k0 += 32) {
        glds16(&A[(size_t)(m0 + srow) * K + k0 + scol],       &As[tid * 8]);
        glds16(&A[(size_t)(m0 + 64 + srow) * K + k0 + scol],  &As[2048 + tid * 8]);
        glds16(&BT[(size_t)(n0 + srow) * K + k0 + scol],      &Bs[tid * 8]);
        glds16(&BT[(size_t)(n0 + 64 + srow) * K + k0 + scol], &Bs[2048 + tid * 8]);
        __syncthreads();
        bf16x8 af[4], bf[4];
#pragma unroll
        for (int i = 0; i < 4; ++i)  af[i] = ldb8(&As[(wm * 64 + i * 16 + c) * 32 + q * 8]);
#pragma unroll
        for (int jn = 0; jn < 4; ++jn) bf[jn] = ldb8(&Bs[(wn * 64 + jn * 16 + c) * 32 + q * 8]);
        // swapped operands: acc[i][jn] holds C[row = ..i..+c][col = ..jn.. + q*4+r]
#pragma unroll
        for (int i = 0; i < 4; ++i)
#pragma unroll
            for (int jn = 0; jn < 4; ++jn)
                acc[i][jn] = MFMA16(bf[jn], af[i], acc[i][jn], 0, 0, 0);
        __syncthreads();
    }
#pragma unroll
    for (int i = 0; i < 4; ++i)
#pragma unroll
        for (int jn = 0; jn < 4; ++jn) {
            int row = m0 + wm * 64 + i * 16 + c;
            int col = n0 + wn * 64 + jn * 16 + q * 4;
            float4 bb = *reinterpret_cast<const float4*>(&bias[col]);
            uint2 w = { pk2(acc[i][jn][0] + bb.x, acc[i][jn][1] + bb.y),
                        pk2(acc[i][jn][2] + bb.z, acc[i][jn][3] + bb.w) };
            *reinterpret_cast<uint2*>(&C[(size_t)row * N + col]) = w;
        }
}

// -------- final GEMM: C[M,N](f32) = A[M,K](bf16) @ BT^T + bias ----------
// 64x128 tile, grid (8, 64).
__global__ __launch_bounds__(256) void gemm_out(
    const u16* __restrict__ A, const u16* __restrict__ BT,
    const float* __restrict__ bias, float* __restrict__ C,
    int M, int N, int K)
{
    __shared__ __align__(16) u16 As[64 * 32];
    __shared__ __align__(16) u16 Bs[128 * 32];
    const int m0 = blockIdx.y * 64, n0 = blockIdx.x * 128;
    const int tid = threadIdx.x, wid = tid >> 6, lane = tid & 63;
    const int q = lane >> 4, c = lane & 15;
    const int wm = wid >> 1, wn = wid & 1;
    const int arow = tid >> 2, acol = (tid & 3) << 3;
    f32x4 acc[2][4] = {};
    for (int k0 = 0; k0 < K; k0 += 32) {
        glds16(&A[(size_t)(m0 + arow) * K + k0 + acol], &As[tid * 8]);
        glds16(&BT[(size_t)(n0 + arow) * K + k0 + acol], &Bs[tid * 8]);
        glds16(&BT[(size_t)(n0 + 64 + arow) * K + k0 + acol], &Bs[2048 + tid * 8]);
        __syncthreads();
        bf16x8 af[2], bf[4];
#pragma unroll
        for (int jm = 0; jm < 2; ++jm) af[jm] = ldb8(&As[(wm * 32 + jm * 16 + c) * 32 + q * 8]);
#pragma unroll
        for (int jn = 0; jn < 4; ++jn) bf[jn] = ldb8(&Bs[(wn * 64 + jn * 16 + c) * 32 + q * 8]);
#pragma unroll
        for (int jm = 0; jm < 2; ++jm)
#pragma unroll
            for (int jn = 0; jn < 4; ++jn)
                acc[jm][jn] = MFMA16(bf[jn], af[jm], acc[jm][jn], 0, 0, 0);
        __syncthreads();
    }
#pragma unroll
    for (int jm = 0; jm < 2; ++jm)
#pragma unroll
        for (int jn = 0; jn < 4; ++jn) {
            int row = m0 + wm * 32 + jm * 16 + c;
            int col = n0 + wn * 64 + jn * 16 + q * 4;
            float4 bb = *reinterpret_cast<const float4*>(&bias[col]);
            float4 v = { acc[jm][jn][0] + bb.x, acc[jm][jn][1] + bb.y,
                         acc[jm][jn][2] + bb.z, acc[jm][jn][3] + bb.w };
            *reinterpret_cast<float4*>(&C[(size_t)row * N + col]) = v;
        }
}

// ---------------- V transpose per head: VT[nh][d][t] --------------------
__global__ __launch_bounds__(256) void vtrans(const u16* __restrict__ V, u16* __restrict__ VT)
{
    __shared__ __align__(16) u16 tile[64 * 72];
    const int nh = blockIdx.y, t0 = blockIdx.x * 64;
    const u16* src = V + (size_t)nh * TS * DH;
    u16* dst = VT + (size_t)nh * DH * TS;
    const int t = threadIdx.x, r = t >> 2, c0 = (t & 3) << 4;
    *reinterpret_cast<uint4*>(&tile[r * 72 + c0]) =
        *reinterpret_cast<const uint4*>(&src[(size_t)(t0 + r) * DH + c0]);
    *reinterpret_cast<uint4*>(&tile[r * 72 + c0 + 8]) =
        *reinterpret_cast<const uint4*>(&src[(size_t)(t0 + r) * DH + c0 + 8]);
    __syncthreads();
    const int d = t >> 2, tc = (t & 3) << 4;
    u16 tmp[16];
#pragma unroll
    for (int j = 0; j < 16; ++j) tmp[j] = tile[(tc + j) * 72 + d];
    *reinterpret_cast<uint4*>(&dst[(size_t)d * TS + t0 + tc]) = *reinterpret_cast<const uint4*>(&tmp[0]);
    *reinterpret_cast<uint4*>(&dst[(size_t)d * TS + t0 + tc + 8]) = *reinterpret_cast<const uint4*>(&tmp[8]);
}

// -------- pass 1: Zfrag = 1/sum_h exp(S/32), S^T fragment order ---------
// grid (32 sb, 16 tb, 2 n); swapped MFMA: lane holds (t = ..+c, s = ..+q*4+r)
__global__ __launch_bounds__(256) void z_kernel(
    const u16* __restrict__ Qp, const u16* __restrict__ Kp, u16* __restrict__ Zf)
{
    __shared__ __align__(16) u16 Ks[64 * 64];
    const int sb = blockIdx.x, tb = blockIdx.y, n = blockIdx.z;
    const int s0 = sb * 64, t0 = tb * 128;
    const int tid = threadIdx.x, wid = tid >> 6, lane = tid & 63;
    const int q = lane >> 4, c = lane & 15;
    const int krow = tid >> 3, kch = tid & 7;
    float zacc[2][4][4] = {};
    for (int h = 0; h < NH; ++h) {
        const u16* Qh = Qp + (size_t)(n * NH + h) * TS * DH;
        const u16* Kh = Kp + (size_t)(n * NH + h) * TS * DH;
        glds16(&Kh[(size_t)(s0 + krow) * DH + ((kch ^ (krow & 7)) << 3)], &Ks[tid * 8]);
        glds16(&Kh[(size_t)(s0 + 32 + krow) * DH + ((kch ^ (krow & 7)) << 3)], &Ks[2048 + tid * 8]);
        __syncthreads();
        bf16x8 qa[2][2], kb[4][2];
#pragma unroll
        for (int jm = 0; jm < 2; ++jm)
#pragma unroll
            for (int kf = 0; kf < 2; ++kf)
                qa[jm][kf] = ldb8(&Qh[(size_t)(t0 + wid * 32 + jm * 16 + c) * DH + kf * 32 + q * 8]);
#pragma unroll
        for (int i = 0; i < 4; ++i)
#pragma unroll
            for (int kf = 0; kf < 2; ++kf)
                kb[i][kf] = ldb8(&Ks[(i * 16 + c) * 64 + (((kf * 4 + q) ^ (c & 7)) << 3)]);
        f32x4 s_[2][4] = {};
#pragma unroll
        for (int kf = 0; kf < 2; ++kf)
#pragma unroll
            for (int jm = 0; jm < 2; ++jm)
#pragma unroll
                for (int i = 0; i < 4; ++i)
                    s_[jm][i] = MFMA16(kb[i][kf], qa[jm][kf], s_[jm][i], 0, 0, 0);
#pragma unroll
        for (int jm = 0; jm < 2; ++jm)
#pragma unroll
            for (int i = 0; i < 4; ++i)
#pragma unroll
                for (int r = 0; r < 4; ++r)
                    zacc[jm][i][r] += __expf(s_[jm][i][r] * SCALE);
        __syncthreads();
    }
    size_t chunk = ((size_t)((n * 32 + sb) * 16 + tb)) * 8192 + wid * 2048 + lane * 32;
#pragma unroll
    for (int jm = 0; jm < 2; ++jm) {
        unsigned w32[8];
#pragma unroll
        for (int i = 0; i < 4; ++i) {
            w32[i * 2 + 0] = pk2(1.0f / zacc[jm][i][0], 1.0f / zacc[jm][i][1]);
            w32[i * 2 + 1] = pk2(1.0f / zacc[jm][i][2], 1.0f / zacc[jm][i][3]);
        }
        *reinterpret_cast<uint4*>(&Zf[chunk + jm * 16])     = *reinterpret_cast<const uint4*>(&w32[0]);
        *reinterpret_cast<uint4*>(&Zf[chunk + jm * 16 + 8]) = *reinterpret_cast<const uint4*>(&w32[4]);
    }
}

// -------- pass 2: out2[h] = (exp(S/32) * Zinv) @ V[h] -------------------
// grid (16 tb, 16 h, 2 n); swapped MFMA throughout; packed P round-trip.
__global__ __launch_bounds__(256) void attn_kernel(
    const u16* __restrict__ Qp, const u16* __restrict__ Kp, const u16* __restrict__ VT,
    const u16* __restrict__ Zf, u16* __restrict__ o2)
{
    __shared__ __align__(16) u16 Ks[64 * 64];
    __shared__ __align__(16) u16 Vs[64 * 64];
    __shared__ __align__(16) u16 Ps[128 * 72];   // [t][s], wave-private t rows
    const int tb = blockIdx.x, h = blockIdx.y, n = blockIdx.z;
    const int t0 = tb * 128;
    const int tid = threadIdx.x, wid = tid >> 6, lane = tid & 63;
    const int q = lane >> 4, c = lane & 15;
    const int krow = tid >> 3, kch = tid & 7;
    const size_t base = (size_t)(n * NH + h) * TS * DH;
    const u16* Qh = Qp + base; const u16* Kh = Kp + base; const u16* VTh = VT + base;
    bf16x8 qa[2][2];
#pragma unroll
    for (int jm = 0; jm < 2; ++jm)
#pragma unroll
        for (int kf = 0; kf < 2; ++kf)
            qa[jm][kf] = ldb8(&Qh[(size_t)(t0 + wid * 32 + jm * 16 + c) * DH + kf * 32 + q * 8]);
    f32x4 oacc[2][4] = {};
    for (int sb = 0; sb < 32; ++sb) {
        const int s0 = sb * 64;
        glds16(&Kh[(size_t)(s0 + krow) * DH + ((kch ^ (krow & 7)) << 3)], &Ks[tid * 8]);
        glds16(&Kh[(size_t)(s0 + 32 + krow) * DH + ((kch ^ (krow & 7)) << 3)], &Ks[2048 + tid * 8]);
        glds16(&VTh[(size_t)krow * TS + s0 + ((kch ^ (krow & 7)) << 3)], &Vs[tid * 8]);
        glds16(&VTh[(size_t)(32 + krow) * TS + s0 + ((kch ^ (krow & 7)) << 3)], &Vs[2048 + tid * 8]);
        __syncthreads();
        bf16x8 kb[4][2];
#pragma unroll
        for (int i = 0; i < 4; ++i)
#pragma unroll
            for (int kf = 0; kf < 2; ++kf)
                kb[i][kf] = ldb8(&Ks[(i * 16 + c) * 64 + (((kf * 4 + q) ^ (c & 7)) << 3)]);
        // swapped: s_[jm][i] holds S[t = wid*32+jm*16+c][s = i*16+q*4+r]
        f32x4 s_[2][4] = {};
#pragma unroll
        for (int kf = 0; kf < 2; ++kf)
#pragma unroll
            for (int jm = 0; jm < 2; ++jm)
#pragma unroll
                for (int i = 0; i < 4; ++i)
                    s_[jm][i] = MFMA16(kb[i][kf], qa[jm][kf], s_[jm][i], 0, 0, 0);
        size_t chunk = ((size_t)((n * 32 + sb) * 16 + tb)) * 8192 + wid * 2048 + lane * 32;
        u16 zl[32];
        *reinterpret_cast<uint4*>(&zl[0])  = *reinterpret_cast<const uint4*>(&Zf[chunk]);
        *reinterpret_cast<uint4*>(&zl[8])  = *reinterpret_cast<const uint4*>(&Zf[chunk + 8]);
        *reinterpret_cast<uint4*>(&zl[16]) = *reinterpret_cast<const uint4*>(&Zf[chunk + 16]);
        *reinterpret_cast<uint4*>(&zl[24]) = *reinterpret_cast<const uint4*>(&Zf[chunk + 24]);
#pragma unroll
        for (int jm = 0; jm < 2; ++jm)
#pragma unroll
            for (int i = 0; i < 4; ++i) {
                float p0 = __expf(s_[jm][i][0] * SCALE) * bf2f(zl[jm * 16 + i * 4 + 0]);
                float p1 = __expf(s_[jm][i][1] * SCALE) * bf2f(zl[jm * 16 + i * 4 + 1]);
                float p2 = __expf(s_[jm][i][2] * SCALE) * bf2f(zl[jm * 16 + i * 4 + 2]);
                float p3 = __expf(s_[jm][i][3] * SCALE) * bf2f(zl[jm * 16 + i * 4 + 3]);
                uint2 w = { pk2(p0, p1), pk2(p2, p3) };
                *reinterpret_cast<uint2*>(&Ps[(wid * 32 + jm * 16 + c) * 72 + i * 16 + q * 4]) = w;
            }
        // wave-private rows: in-wave LDS dep handled via lgkmcnt, no barrier
        bf16x8 pa[2][2], vb[4][2];
#pragma unroll
        for (int jm = 0; jm < 2; ++jm)
#pragma unroll
            for (int kf = 0; kf < 2; ++kf)
                pa[jm][kf] = ldb8(&Ps[(wid * 32 + jm * 16 + c) * 72 + kf * 32 + q * 8]);
#pragma unroll
        for (int dn = 0; dn < 4; ++dn)
#pragma unroll
            for (int kf = 0; kf < 2; ++kf)
                vb[dn][kf] = ldb8(&Vs[(dn * 16 + c) * 64 + (((kf * 4 + q) ^ (c & 7)) << 3)]);
        // swapped: oacc[jm][dn] holds O[t = ..jm..+c][d = dn*16 + q*4+r]
#pragma unroll
        for (int kf = 0; kf < 2; ++kf)
#pragma unroll
            for (int jm = 0; jm < 2; ++jm)
#pragma unroll
                for (int dn = 0; dn < 4; ++dn)
                    oacc[jm][dn] = MFMA16(vb[dn][kf], pa[jm][kf], oacc[jm][dn], 0, 0, 0);
        __syncthreads();
    }
#pragma unroll
    for (int jm = 0; jm < 2; ++jm)
#pragma unroll
        for (int dn = 0; dn < 4; ++dn) {
            int t = t0 + wid * 32 + jm * 16 + c;
            int d = dn * 16 + q * 4;
            uint2 w = { pk2(oacc[jm][dn][0], oacc[jm][dn][1]),
                        pk2(oacc[jm][dn][2], oacc[jm][dn][3]) };
            *reinterpret_cast<uint2*>(&o2[base + (size_t)t * DH + d]) = w;
        }
}

extern "C" void kernel_launch(void* const* d_in, const int* in_sizes, int n_in,
                              void* d_out, int out_size, void* d_ws, size_t ws_size,
                              hipStream_t stream)
{
    const float* q  = (const float*)d_in[0];
    const float* k  = (const float*)d_in[1];
    const float* v  = (const float*)d_in[2];
    const float* Wq = (const float*)d_in[3];
    const float* bq = (const float*)d_in[4];
    const float* Wk = (const float*)d_in[5];
    const float* bk = (const float*)d_in[6];
    const float* Wv = (const float*)d_in[7];
    const float* bv = (const float*)d_in[8];
    const float* Wo = (const float*)d_in[9];
    const float* bo = (const float*)d_in[10];
    float* out = (float*)d_out;

    // ws (u16 elems), 56 MiB total:
    //   wT x4 (2 MiB each) + S1..S6 (8 MiB each).
    //   qb=S1 kb=S2 vb=S3  Qp=S4 Kp=S5 Vp=S6 (all live during gemm_qkv)
    //   VTb=S1 (qb dead), Zf=S2..S3 (16 MiB, kb/vb dead), o2=S6 (Vp dead)
    u16* ws  = (u16*)d_ws;
    u16* wqT = ws + 0 * 1048576;
    u16* wkT = ws + 1 * 1048576;
    u16* wvT = ws + 2 * 1048576;
    u16* woT = ws + 3 * 1048576;
    u16* S1  = ws + 4194304;
    u16* S2  = S1 + 4194304;
    u16* S3  = S2 + 4194304;
    u16* S4  = S3 + 4194304;
    u16* S5  = S4 + 4194304;
    u16* S6  = S5 + 4194304;
    (void)S3;
    u16 *qb = S1, *kb = S2, *vb = S3;
    u16 *Qp = S4, *Kp = S5, *Vp = S6;
    u16 *VTb = S1, *Zf = S2, *o2 = S6;

    to_bf16<<<dim3(2048, 3), 256, 0, stream>>>(q, k, v, qb, kb, vb);
    wtrans<<<dim3(16, 16, 4), 256, 0, stream>>>(Wq, Wk, Wv, Wo, wqT, wkT, wvT, woT);
    gemm_qkv<<<dim3(8, 32, 3), 256, 0, stream>>>(qb, kb, vb, wqT, wkT, wvT,
                                                 bq, bk, bv, Qp, Kp, Vp);
    vtrans<<<dim3(32, 32), 256, 0, stream>>>(Vp, VTb);
    z_kernel<<<dim3(32, 16, 2), 256, 0, stream>>>(Qp, Kp, Zf);
    attn_kernel<<<dim3(16, 16, 2), 256, 0, stream>>>(Qp, Kp, VTb, Zf, o2);
    gemm_out<<<dim3(8, 64), 256, 0, stream>>>(o2, woT, bo, out, NB * TS, HD, HD);
}

// Round 6
// 304.139 us; speedup vs baseline: 1.3859x; 1.0653x over previous
//
#include <hip/hip_runtime.h>

typedef unsigned short u16;
typedef __bf16 bf16x8 __attribute__((ext_vector_type(8)));
typedef float f32x4 __attribute__((ext_vector_type(4)));

#define MFMA16 __builtin_amdgcn_mfma_f32_16x16x32_bf16

constexpr int NB = 2, TS = 2048, HD = 1024, NH = 16, DH = 64;
// SCALE * log2(e): folded into Wq/bq so softmax uses raw exp2
constexpr float ALPHA = 0.045084220027780106f;

__device__ __forceinline__ u16 f2bf(float f) {
    union { float f; unsigned u; } v; v.f = f;
    unsigned r = v.u + 0x7FFFu + ((v.u >> 16) & 1u);  // RNE
    return (u16)(r >> 16);
}
__device__ __forceinline__ float bf2f(u16 h) {
    union { unsigned u; float f; } v; v.u = ((unsigned)h) << 16;
    return v.f;
}
__device__ __forceinline__ bf16x8 ldb8(const u16* p) {
    return *reinterpret_cast<const bf16x8*>(p);
}
__device__ __forceinline__ void glds16(const u16* g, u16* l) {
    __builtin_amdgcn_global_load_lds(
        (const __attribute__((address_space(1))) unsigned int*)g,
        (__attribute__((address_space(3))) unsigned int*)l, 16, 0, 0);
}

#if defined(__has_builtin)
#  if __has_builtin(__builtin_amdgcn_cvt_pk_bf16_f32)
#    define HAVE_PKBF16 1
#  endif
#  if __has_builtin(__builtin_amdgcn_exp2f)
#    define HAVE_EXP2 1
#  endif
#endif
#ifndef HAVE_PKBF16
#  define HAVE_PKBF16 0
#endif
#ifndef HAVE_EXP2
#  define HAVE_EXP2 0
#endif
__device__ __forceinline__ unsigned pk2(float a, float b) {
#if HAVE_PKBF16
    typedef __bf16 bf16x2 __attribute__((ext_vector_type(2)));
    bf16x2 r = __builtin_amdgcn_cvt_pk_bf16_f32(a, b);
    return __builtin_bit_cast(unsigned, r);
#else
    return (unsigned)f2bf(a) | ((unsigned)f2bf(b) << 16);
#endif
}
__device__ __forceinline__ float fexp2(float x) {
#if HAVE_EXP2
    return __builtin_amdgcn_exp2f(x);
#else
    return exp2f(x);
#endif
}

// ---------------- fp32 -> bf16 bulk convert (q,k,v) ---------------------
__global__ __launch_bounds__(256) void to_bf16(
    const float* __restrict__ a0, const float* __restrict__ a1, const float* __restrict__ a2,
    u16* __restrict__ o0, u16* __restrict__ o1, u16* __restrict__ o2)
{
    const float* s; u16* d;
    if (blockIdx.y == 0)      { s = a0; d = o0; }
    else if (blockIdx.y == 1) { s = a1; d = o1; }
    else                      { s = a2; d = o2; }
    size_t i = ((size_t)blockIdx.x * 256 + threadIdx.x) * 8;
    float4 v0 = *reinterpret_cast<const float4*>(s + i);
    float4 v1 = *reinterpret_cast<const float4*>(s + i + 4);
    uint4 w = { pk2(v0.x, v0.y), pk2(v0.z, v0.w), pk2(v1.x, v1.y), pk2(v1.z, v1.w) };
    *reinterpret_cast<uint4*>(d + i) = w;
}

// ------------- weight transpose + fp32->bf16 (+ALPHA on Wq) -------------
__global__ __launch_bounds__(256) void wtrans(
    const float* __restrict__ w0, const float* __restrict__ w1,
    const float* __restrict__ w2, const float* __restrict__ w3,
    u16* __restrict__ o0, u16* __restrict__ o1,
    u16* __restrict__ o2, u16* __restrict__ o3)
{
    const float* src; u16* dst; float sc;
    if (blockIdx.z == 0)      { src = w0; dst = o0; sc = ALPHA; }
    else if (blockIdx.z == 1) { src = w1; dst = o1; sc = 1.0f; }
    else if (blockIdx.z == 2) { src = w2; dst = o2; sc = 1.0f; }
    else                      { src = w3; dst = o3; sc = 1.0f; }
    __shared__ __align__(16) u16 tile[64 * 72];
    const int k0 = blockIdx.y * 64, n0 = blockIdx.x * 64;
    const int t = threadIdx.x, r = t >> 2, c0 = (t & 3) << 4;
#pragma unroll
    for (int j = 0; j < 4; ++j) {
        float4 v = *reinterpret_cast<const float4*>(&src[(size_t)(k0 + r) * HD + n0 + c0 + 4 * j]);
        tile[(c0 + 4 * j + 0) * 72 + r] = f2bf(v.x * sc);
        tile[(c0 + 4 * j + 1) * 72 + r] = f2bf(v.y * sc);
        tile[(c0 + 4 * j + 2) * 72 + r] = f2bf(v.z * sc);
        tile[(c0 + 4 * j + 3) * 72 + r] = f2bf(v.w * sc);
    }
    __syncthreads();
#pragma unroll
    for (int j = 0; j < 2; ++j)
        *reinterpret_cast<uint4*>(&dst[(size_t)(n0 + r) * HD + k0 + c0 + 8 * j]) =
            *reinterpret_cast<const uint4*>(&tile[r * 72 + c0 + 8 * j]);
}

// -------- merged Q/K/V projection GEMM, 128x128 tile --------------------
// z==0: Q (ALPHA-scaled). z==2: writes V^T [n,h][d][tau] directly, honoring
// the quirky reshape: flat = t_proj*1024 + col = h*131072 + tau*64 + d
//   => h = t_proj>>7, tau = (t_proj&127)*16 + (col>>6), d = col&63.
__global__ __launch_bounds__(256) void gemm_qkv(
    const u16* __restrict__ A0, const u16* __restrict__ A1, const u16* __restrict__ A2,
    const u16* __restrict__ B0, const u16* __restrict__ B1, const u16* __restrict__ B2,
    const float* __restrict__ c0, const float* __restrict__ c1, const float* __restrict__ c2,
    u16* __restrict__ C0, u16* __restrict__ C1, u16* __restrict__ VT)
{
    const u16 *A, *BT; const float* bias;
    if (blockIdx.z == 0)      { A = A0; BT = B0; bias = c0; }
    else if (blockIdx.z == 1) { A = A1; BT = B1; bias = c1; }
    else                      { A = A2; BT = B2; bias = c2; }
    constexpr int N = HD, K = HD;
    __shared__ __align__(16) u16 As[128 * 32];
    __shared__ __align__(16) u16 Bs[128 * 32];
    const int m0 = blockIdx.y * 128, n0 = blockIdx.x * 128;
    const int tid = threadIdx.x, wid = tid >> 6, lane = tid & 63;
    const int q = lane >> 4, c = lane & 15;
    const int wm = wid >> 1, wn = wid & 1;
    const int srow = tid >> 2, scol = (tid & 3) << 3;
    f32x4 acc[4][4] = {};
    for (int k0 = 0; k0 < K; k0 += 32) {
        glds16(&A[(size_t)(m0 + srow) * K + k0 + scol],       &As[tid * 8]);
        glds16(&A[(size_t)(m0 + 64 + srow) * K + k0 + scol],  &As[2048 + tid * 8]);
        glds16(&BT[(size_t)(n0 + srow) * K + k0 + scol],      &Bs[tid * 8]);
        glds16(&BT[(size_t)(n0 + 64 + srow) * K + k0 + scol], &Bs[2048 + tid * 8]);
        __syncthreads();
        bf16x8 af[4], bf[4];
#pragma unroll
        for (int i = 0; i < 4; ++i)  af[i] = ldb8(&As[(wm * 64 + i * 16 + c) * 32 + q * 8]);
#pragma unroll
        for (int jn = 0; jn < 4; ++jn) bf[jn] = ldb8(&Bs[(wn * 64 + jn * 16 + c) * 32 + q * 8]);
#pragma unroll
        for (int i = 0; i < 4; ++i)
#pragma unroll
            for (int jn = 0; jn < 4; ++jn)
                acc[i][jn] = MFMA16(bf[jn], af[i], acc[i][jn], 0, 0, 0);
        __syncthreads();
    }
    if (blockIdx.z == 2) {
#pragma unroll
        for (int i = 0; i < 4; ++i)
#pragma unroll
            for (int jn = 0; jn < 4; ++jn) {
                int row = m0 + wm * 64 + i * 16 + c;        // (n, t_proj)
                int nn = row >> 11, tp = row & 2047;
                int col = n0 + wn * 64 + jn * 16 + q * 4;   // hidden col
                int hh  = tp >> 7;
                int tau = ((tp & 127) << 4) + (col >> 6);
                int d0  = col & 63;                          // +r stays < 64
#pragma unroll
                for (int r = 0; r < 4; ++r)
                    VT[(size_t)((nn * 16 + hh) * 64 + d0 + r) * 2048 + tau] =
                        f2bf(acc[i][jn][r] + bias[col + r]);
            }
    } else {
        u16* C = (blockIdx.z == 0) ? C0 : C1;
        const float bsc = (blockIdx.z == 0) ? ALPHA : 1.0f;
#pragma unroll
        for (int i = 0; i < 4; ++i)
#pragma unroll
            for (int jn = 0; jn < 4; ++jn) {
                int row = m0 + wm * 64 + i * 16 + c;
                int col = n0 + wn * 64 + jn * 16 + q * 4;
                float4 bb = *reinterpret_cast<const float4*>(&bias[col]);
                uint2 w = { pk2(acc[i][jn][0] + bb.x * bsc, acc[i][jn][1] + bb.y * bsc),
                            pk2(acc[i][jn][2] + bb.z * bsc, acc[i][jn][3] + bb.w * bsc) };
                *reinterpret_cast<uint2*>(&C[(size_t)row * N + col]) = w;
            }
    }
}

// -------- final GEMM: C[M,N](f32) = A[M,K](bf16) @ BT^T + bias ----------
__global__ __launch_bounds__(256) void gemm_out(
    const u16* __restrict__ A, const u16* __restrict__ BT,
    const float* __restrict__ bias, float* __restrict__ C,
    int M, int N, int K)
{
    __shared__ __align__(16) u16 As[64 * 32];
    __shared__ __align__(16) u16 Bs[128 * 32];
    const int m0 = blockIdx.y * 64, n0 = blockIdx.x * 128;
    const int tid = threadIdx.x, wid = tid >> 6, lane = tid & 63;
    const int q = lane >> 4, c = lane & 15;
    const int wm = wid >> 1, wn = wid & 1;
    const int arow = tid >> 2, acol = (tid & 3) << 3;
    f32x4 acc[2][4] = {};
    for (int k0 = 0; k0 < K; k0 += 32) {
        glds16(&A[(size_t)(m0 + arow) * K + k0 + acol], &As[tid * 8]);
        glds16(&BT[(size_t)(n0 + arow) * K + k0 + acol], &Bs[tid * 8]);
        glds16(&BT[(size_t)(n0 + 64 + arow) * K + k0 + acol], &Bs[2048 + tid * 8]);
        __syncthreads();
        bf16x8 af[2], bf[4];
#pragma unroll
        for (int jm = 0; jm < 2; ++jm) af[jm] = ldb8(&As[(wm * 32 + jm * 16 + c) * 32 + q * 8]);
#pragma unroll
        for (int jn = 0; jn < 4; ++jn) bf[jn] = ldb8(&Bs[(wn * 64 + jn * 16 + c) * 32 + q * 8]);
#pragma unroll
        for (int jm = 0; jm < 2; ++jm)
#pragma unroll
            for (int jn = 0; jn < 4; ++jn)
                acc[jm][jn] = MFMA16(bf[jn], af[jm], acc[jm][jn], 0, 0, 0);
        __syncthreads();
    }
#pragma unroll
    for (int jm = 0; jm < 2; ++jm)
#pragma unroll
        for (int jn = 0; jn < 4; ++jn) {
            int row = m0 + wm * 32 + jm * 16 + c;
            int col = n0 + wn * 64 + jn * 16 + q * 4;
            float4 bb = *reinterpret_cast<const float4*>(&bias[col]);
            float4 v = { acc[jm][jn][0] + bb.x, acc[jm][jn][1] + bb.y,
                         acc[jm][jn][2] + bb.z, acc[jm][jn][3] + bb.w };
            *reinterpret_cast<float4*>(&C[(size_t)row * N + col]) = v;
        }
}

// -------- pass 1: Zf = 1/sum_h exp2(S'), frag-row layout ----------------
// grid (32 sb, 16 tb, 2 n); t-tile 128, Q+K staged via glds.
// Zf[((n*32+sb)*2048 + t)*64 + q*16 + i*4 + r], s = sb*64 + i*16 + q*4 + r
__global__ __launch_bounds__(256) void z_kernel(
    const u16* __restrict__ Qp, const u16* __restrict__ Kp, u16* __restrict__ Zf)
{
    __shared__ __align__(16) u16 Ks[64 * 64];
    __shared__ __align__(16) u16 Qs[128 * 64];
    const int sb = blockIdx.x, tb = blockIdx.y, n = blockIdx.z;
    const int s0 = sb * 64, t0 = tb * 128;
    const int tid = threadIdx.x, wid = tid >> 6, lane = tid & 63;
    const int q = lane >> 4, c = lane & 15;
    const int krow = tid >> 3, kch = tid & 7;
    float zacc[2][4][4] = {};
    for (int h = 0; h < NH; ++h) {
        const u16* Qh = Qp + (size_t)(n * NH + h) * TS * DH;
        const u16* Kh = Kp + (size_t)(n * NH + h) * TS * DH;
        glds16(&Kh[(size_t)(s0 + krow) * DH + ((kch ^ (krow & 7)) << 3)], &Ks[tid * 8]);
        glds16(&Kh[(size_t)(s0 + 32 + krow) * DH + ((kch ^ (krow & 7)) << 3)], &Ks[2048 + tid * 8]);
#pragma unroll
        for (int L = 0; L < 4; ++L)
            glds16(&Qh[(size_t)(t0 + L * 32 + krow) * DH + ((kch ^ (krow & 7)) << 3)],
                   &Qs[L * 2048 + tid * 8]);
        __syncthreads();
        bf16x8 qa[2][2], kb[4][2];
#pragma unroll
        for (int jm = 0; jm < 2; ++jm)
#pragma unroll
            for (int kf = 0; kf < 2; ++kf)
                qa[jm][kf] = ldb8(&Qs[(wid * 32 + jm * 16 + c) * 64 + (((kf * 4 + q) ^ (c & 7)) << 3)]);
#pragma unroll
        for (int i = 0; i < 4; ++i)
#pragma unroll
            for (int kf = 0; kf < 2; ++kf)
                kb[i][kf] = ldb8(&Ks[(i * 16 + c) * 64 + (((kf * 4 + q) ^ (c & 7)) << 3)]);
        f32x4 s_[2][4] = {};
#pragma unroll
        for (int kf = 0; kf < 2; ++kf)
#pragma unroll
            for (int jm = 0; jm < 2; ++jm)
#pragma unroll
                for (int i = 0; i < 4; ++i)
                    s_[jm][i] = MFMA16(kb[i][kf], qa[jm][kf], s_[jm][i], 0, 0, 0);
#pragma unroll
        for (int jm = 0; jm < 2; ++jm)
#pragma unroll
            for (int i = 0; i < 4; ++i)
#pragma unroll
                for (int r = 0; r < 4; ++r)
                    zacc[jm][i][r] += fexp2(s_[jm][i][r]);
        __syncthreads();
    }
#pragma unroll
    for (int jm = 0; jm < 2; ++jm) {
        int t = t0 + wid * 32 + jm * 16 + c;
        size_t zb = ((size_t)((n * 32 + sb) * 2048) + t) * 64 + q * 16;
        unsigned w32[8];
#pragma unroll
        for (int i = 0; i < 4; ++i) {
            w32[i * 2 + 0] = pk2(1.0f / zacc[jm][i][0], 1.0f / zacc[jm][i][1]);
            w32[i * 2 + 1] = pk2(1.0f / zacc[jm][i][2], 1.0f / zacc[jm][i][3]);
        }
        *reinterpret_cast<uint4*>(&Zf[zb])     = *reinterpret_cast<const uint4*>(&w32[0]);
        *reinterpret_cast<uint4*>(&Zf[zb + 8]) = *reinterpret_cast<const uint4*>(&w32[4]);
    }
}

// -------- pass 2: out2[h] = (exp2(S') * Zinv) @ V[h] --------------------
// grid (32 tb, 16 h, 2 n); t-tile 64 (4 waves x 16t) for 4 blocks/CU.
__global__ __launch_bounds__(256) void attn_kernel(
    const u16* __restrict__ Qp, const u16* __restrict__ Kp, const u16* __restrict__ VT,
    const u16* __restrict__ Zf, u16* __restrict__ o2)
{
    __shared__ __align__(16) u16 Ks[64 * 64];
    __shared__ __align__(16) u16 Vs[64 * 64];
    __shared__ __align__(16) u16 Ps[64 * 72];   // [t][s], wave-private 16-row bands
    const int tb = blockIdx.x, h = blockIdx.y, n = blockIdx.z;
    const int t0 = tb * 64;
    const int tid = threadIdx.x, wid = tid >> 6, lane = tid & 63;
    const int q = lane >> 4, c = lane & 15;
    const int krow = tid >> 3, kch = tid & 7;
    const size_t base = (size_t)(n * NH + h) * TS * DH;
    const u16* Qh = Qp + base; const u16* Kh = Kp + base; const u16* VTh = VT + base;
    const int tme = t0 + wid * 16 + c;          // this lane's t row
    bf16x8 qa[2];
#pragma unroll
    for (int kf = 0; kf < 2; ++kf)
        qa[kf] = ldb8(&Qh[(size_t)tme * DH + kf * 32 + q * 8]);
    f32x4 oacc[4] = {};
    for (int sb = 0; sb < 32; ++sb) {
        const int s0 = sb * 64;
        glds16(&Kh[(size_t)(s0 + krow) * DH + ((kch ^ (krow & 7)) << 3)], &Ks[tid * 8]);
        glds16(&Kh[(size_t)(s0 + 32 + krow) * DH + ((kch ^ (krow & 7)) << 3)], &Ks[2048 + tid * 8]);
        glds16(&VTh[(size_t)krow * TS + s0 + ((kch ^ (krow & 7)) << 3)], &Vs[tid * 8]);
        glds16(&VTh[(size_t)(32 + krow) * TS + s0 + ((kch ^ (krow & 7)) << 3)], &Vs[2048 + tid * 8]);
        // Zinv for this lane's t row, s-fragment order: 2x16B
        size_t zb = ((size_t)((n * 32 + sb) * 2048) + tme) * 64 + q * 16;
        u16 zl[16];
        *reinterpret_cast<uint4*>(&zl[0]) = *reinterpret_cast<const uint4*>(&Zf[zb]);
        *reinterpret_cast<uint4*>(&zl[8]) = *reinterpret_cast<const uint4*>(&Zf[zb + 8]);
        __syncthreads();
        bf16x8 kb[4][2];
#pragma unroll
        for (int i = 0; i < 4; ++i)
#pragma unroll
            for (int kf = 0; kf < 2; ++kf)
                kb[i][kf] = ldb8(&Ks[(i * 16 + c) * 64 + (((kf * 4 + q) ^ (c & 7)) << 3)]);
        f32x4 s_[4] = {};
#pragma unroll
        for (int kf = 0; kf < 2; ++kf)
#pragma unroll
            for (int i = 0; i < 4; ++i)
                s_[i] = MFMA16(kb[i][kf], qa[kf], s_[i], 0, 0, 0);
#pragma unroll
        for (int i = 0; i < 4; ++i) {
            float p0 = fexp2(s_[i][0]) * bf2f(zl[i * 4 + 0]);
            float p1 = fexp2(s_[i][1]) * bf2f(zl[i * 4 + 1]);
            float p2 = fexp2(s_[i][2]) * bf2f(zl[i * 4 + 2]);
            float p3 = fexp2(s_[i][3]) * bf2f(zl[i * 4 + 3]);
            uint2 w = { pk2(p0, p1), pk2(p2, p3) };
            *reinterpret_cast<uint2*>(&Ps[(wid * 16 + c) * 72 + i * 16 + q * 4]) = w;
        }
        bf16x8 pa[2], vb[4][2];
#pragma unroll
        for (int kf = 0; kf < 2; ++kf)
            pa[kf] = ldb8(&Ps[(wid * 16 + c) * 72 + kf * 32 + q * 8]);
#pragma unroll
        for (int dn = 0; dn < 4; ++dn)
#pragma unroll
            for (int kf = 0; kf < 2; ++kf)
                vb[dn][kf] = ldb8(&Vs[(dn * 16 + c) * 64 + (((kf * 4 + q) ^ (c & 7)) << 3)]);
#pragma unroll
        for (int kf = 0; kf < 2; ++kf)
#pragma unroll
            for (int dn = 0; dn < 4; ++dn)
                oacc[dn] = MFMA16(vb[dn][kf], pa[kf], oacc[dn], 0, 0, 0);
        __syncthreads();
    }
#pragma unroll
    for (int dn = 0; dn < 4; ++dn) {
        uint2 w = { pk2(oacc[dn][0], oacc[dn][1]), pk2(oacc[dn][2], oacc[dn][3]) };
        *reinterpret_cast<uint2*>(&o2[base + (size_t)tme * DH + dn * 16 + q * 4]) = w;
    }
}

extern "C" void kernel_launch(void* const* d_in, const int* in_sizes, int n_in,
                              void* d_out, int out_size, void* d_ws, size_t ws_size,
                              hipStream_t stream)
{
    const float* q  = (const float*)d_in[0];
    const float* k  = (const float*)d_in[1];
    const float* v  = (const float*)d_in[2];
    const float* Wq = (const float*)d_in[3];
    const float* bq = (const float*)d_in[4];
    const float* Wk = (const float*)d_in[5];
    const float* bk = (const float*)d_in[6];
    const float* Wv = (const float*)d_in[7];
    const float* bv = (const float*)d_in[8];
    const float* Wo = (const float*)d_in[9];
    const float* bo = (const float*)d_in[10];
    float* out = (float*)d_out;

    // ws (u16 elems), 56 MiB: wT x4 (2 MiB) + S1..S6 (8 MiB each)
    //   qb=S1 kb=S2 vb=S3 (dead after gemm_qkv)  Qp=S4 Kp=S5 VTb=S6
    //   Zf=S1..S2 (16 MiB)  o2=S3
    u16* ws  = (u16*)d_ws;
    u16* wqT = ws + 0 * 1048576;
    u16* wkT = ws + 1 * 1048576;
    u16* wvT = ws + 2 * 1048576;
    u16* woT = ws + 3 * 1048576;
    u16* S1  = ws + 4194304;
    u16* S2  = S1 + 4194304;
    u16* S3  = S2 + 4194304;
    u16* S4  = S3 + 4194304;
    u16* S5  = S4 + 4194304;
    u16* S6  = S5 + 4194304;
    u16 *qb = S1, *kb = S2, *vb = S3;
    u16 *Qp = S4, *Kp = S5, *VTb = S6;
    u16 *Zf = S1, *o2 = S3;

    to_bf16<<<dim3(2048, 3), 256, 0, stream>>>(q, k, v, qb, kb, vb);
    wtrans<<<dim3(16, 16, 4), 256, 0, stream>>>(Wq, Wk, Wv, Wo, wqT, wkT, wvT, woT);
    gemm_qkv<<<dim3(8, 32, 3), 256, 0, stream>>>(qb, kb, vb, wqT, wkT, wvT,
                                                 bq, bk, bv, Qp, Kp, VTb);
    z_kernel<<<dim3(32, 16, 2), 256, 0, stream>>>(Qp, Kp, Zf);
    attn_kernel<<<dim3(32, 16, 2), 256, 0, stream>>>(Qp, Kp, VTb, Zf, o2);
    gemm_out<<<dim3(8, 64), 256, 0, stream>>>(o2, woT, bo, out, NB * TS, HD, HD);
}

// Round 7
// 295.367 us; speedup vs baseline: 1.4271x; 1.0297x over previous
//
#include <hip/hip_runtime.h>

typedef unsigned short u16;
typedef __bf16 bf16x8 __attribute__((ext_vector_type(8)));
typedef float f32x4 __attribute__((ext_vector_type(4)));

#define MFMA16 __builtin_amdgcn_mfma_f32_16x16x32_bf16

constexpr int NB = 2, TS = 2048, HD = 1024, NH = 16, DH = 64;
// SCALE * log2(e): folded into Wq/bq so softmax uses raw exp2
constexpr float ALPHA = 0.045084220027780106f;

__device__ __forceinline__ u16 f2bf(float f) {
    union { float f; unsigned u; } v; v.f = f;
    unsigned r = v.u + 0x7FFFu + ((v.u >> 16) & 1u);  // RNE
    return (u16)(r >> 16);
}
__device__ __forceinline__ float bf2f(u16 h) {
    union { unsigned u; float f; } v; v.u = ((unsigned)h) << 16;
    return v.f;
}
__device__ __forceinline__ bf16x8 ldb8(const u16* p) {
    return *reinterpret_cast<const bf16x8*>(p);
}
__device__ __forceinline__ void glds16(const u16* g, u16* l) {
    __builtin_amdgcn_global_load_lds(
        (const __attribute__((address_space(1))) unsigned int*)g,
        (__attribute__((address_space(3))) unsigned int*)l, 16, 0, 0);
}

#if defined(__has_builtin)
#  if __has_builtin(__builtin_amdgcn_cvt_pk_bf16_f32)
#    define HAVE_PKBF16 1
#  endif
#  if __has_builtin(__builtin_amdgcn_exp2f)
#    define HAVE_EXP2 1
#  endif
#endif
#ifndef HAVE_PKBF16
#  define HAVE_PKBF16 0
#endif
#ifndef HAVE_EXP2
#  define HAVE_EXP2 0
#endif
__device__ __forceinline__ unsigned pk2(float a, float b) {
#if HAVE_PKBF16
    typedef __bf16 bf16x2 __attribute__((ext_vector_type(2)));
    bf16x2 r = __builtin_amdgcn_cvt_pk_bf16_f32(a, b);
    return __builtin_bit_cast(unsigned, r);
#else
    return (unsigned)f2bf(a) | ((unsigned)f2bf(b) << 16);
#endif
}
__device__ __forceinline__ float fexp2(float x) {
#if HAVE_EXP2
    return __builtin_amdgcn_exp2f(x);
#else
    return exp2f(x);
#endif
}

// ---------------- fp32 -> bf16 bulk convert (q,k,v) ---------------------
__global__ __launch_bounds__(256) void to_bf16(
    const float* __restrict__ a0, const float* __restrict__ a1, const float* __restrict__ a2,
    u16* __restrict__ o0, u16* __restrict__ o1, u16* __restrict__ o2)
{
    const float* s; u16* d;
    if (blockIdx.y == 0)      { s = a0; d = o0; }
    else if (blockIdx.y == 1) { s = a1; d = o1; }
    else                      { s = a2; d = o2; }
    size_t i = ((size_t)blockIdx.x * 256 + threadIdx.x) * 8;
    float4 v0 = *reinterpret_cast<const float4*>(s + i);
    float4 v1 = *reinterpret_cast<const float4*>(s + i + 4);
    uint4 w = { pk2(v0.x, v0.y), pk2(v0.z, v0.w), pk2(v1.x, v1.y), pk2(v1.z, v1.w) };
    *reinterpret_cast<uint4*>(d + i) = w;
}

// ------------- weight transpose + fp32->bf16 (+ALPHA on Wq) -------------
__global__ __launch_bounds__(256) void wtrans(
    const float* __restrict__ w0, const float* __restrict__ w1,
    const float* __restrict__ w2, const float* __restrict__ w3,
    u16* __restrict__ o0, u16* __restrict__ o1,
    u16* __restrict__ o2, u16* __restrict__ o3)
{
    const float* src; u16* dst; float sc;
    if (blockIdx.z == 0)      { src = w0; dst = o0; sc = ALPHA; }
    else if (blockIdx.z == 1) { src = w1; dst = o1; sc = 1.0f; }
    else if (blockIdx.z == 2) { src = w2; dst = o2; sc = 1.0f; }
    else                      { src = w3; dst = o3; sc = 1.0f; }
    __shared__ __align__(16) u16 tile[64 * 72];
    const int k0 = blockIdx.y * 64, n0 = blockIdx.x * 64;
    const int t = threadIdx.x, r = t >> 2, c0 = (t & 3) << 4;
#pragma unroll
    for (int j = 0; j < 4; ++j) {
        float4 v = *reinterpret_cast<const float4*>(&src[(size_t)(k0 + r) * HD + n0 + c0 + 4 * j]);
        tile[(c0 + 4 * j + 0) * 72 + r] = f2bf(v.x * sc);
        tile[(c0 + 4 * j + 1) * 72 + r] = f2bf(v.y * sc);
        tile[(c0 + 4 * j + 2) * 72 + r] = f2bf(v.z * sc);
        tile[(c0 + 4 * j + 3) * 72 + r] = f2bf(v.w * sc);
    }
    __syncthreads();
#pragma unroll
    for (int j = 0; j < 2; ++j)
        *reinterpret_cast<uint4*>(&dst[(size_t)(n0 + r) * HD + k0 + c0 + 8 * j]) =
            *reinterpret_cast<const uint4*>(&tile[r * 72 + c0 + 8 * j]);
}

// -------- merged Q/K/V projection GEMM, 128x128 tile --------------------
// Uniform packed epilogue for all three slices (V written flat: the flat
// [t_proj][col] layout IS the quirky per-head layout by reinterpretation).
__global__ __launch_bounds__(256) void gemm_qkv(
    const u16* __restrict__ A0, const u16* __restrict__ A1, const u16* __restrict__ A2,
    const u16* __restrict__ B0, const u16* __restrict__ B1, const u16* __restrict__ B2,
    const float* __restrict__ c0, const float* __restrict__ c1, const float* __restrict__ c2,
    u16* __restrict__ C0, u16* __restrict__ C1, u16* __restrict__ C2)
{
    const u16 *A, *BT; const float* bias; u16* C; float bsc;
    if (blockIdx.z == 0)      { A = A0; BT = B0; bias = c0; C = C0; bsc = ALPHA; }
    else if (blockIdx.z == 1) { A = A1; BT = B1; bias = c1; C = C1; bsc = 1.0f; }
    else                      { A = A2; BT = B2; bias = c2; C = C2; bsc = 1.0f; }
    constexpr int N = HD, K = HD;
    __shared__ __align__(16) u16 As[128 * 32];
    __shared__ __align__(16) u16 Bs[128 * 32];
    const int m0 = blockIdx.y * 128, n0 = blockIdx.x * 128;
    const int tid = threadIdx.x, wid = tid >> 6, lane = tid & 63;
    const int q = lane >> 4, c = lane & 15;
    const int wm = wid >> 1, wn = wid & 1;
    const int srow = tid >> 2, scol = (tid & 3) << 3;
    const u16* ag0 = A + (size_t)(m0 + srow) * K + scol;
    const u16* ag1 = A + (size_t)(m0 + 64 + srow) * K + scol;
    const u16* bg0 = BT + (size_t)(n0 + srow) * K + scol;
    const u16* bg1 = BT + (size_t)(n0 + 64 + srow) * K + scol;
    f32x4 acc[4][4] = {};
    for (int k0 = 0; k0 < K; k0 += 32) {
        glds16(ag0, &As[tid * 8]);
        glds16(ag1, &As[2048 + tid * 8]);
        glds16(bg0, &Bs[tid * 8]);
        glds16(bg1, &Bs[2048 + tid * 8]);
        ag0 += 32; ag1 += 32; bg0 += 32; bg1 += 32;
        __syncthreads();
        bf16x8 af[4], bf[4];
#pragma unroll
        for (int i = 0; i < 4; ++i)  af[i] = ldb8(&As[(wm * 64 + i * 16 + c) * 32 + q * 8]);
#pragma unroll
        for (int jn = 0; jn < 4; ++jn) bf[jn] = ldb8(&Bs[(wn * 64 + jn * 16 + c) * 32 + q * 8]);
#pragma unroll
        for (int i = 0; i < 4; ++i)
#pragma unroll
            for (int jn = 0; jn < 4; ++jn)
                acc[i][jn] = MFMA16(bf[jn], af[i], acc[i][jn], 0, 0, 0);
        __syncthreads();
    }
#pragma unroll
    for (int i = 0; i < 4; ++i)
#pragma unroll
        for (int jn = 0; jn < 4; ++jn) {
            int row = m0 + wm * 64 + i * 16 + c;
            int col = n0 + wn * 64 + jn * 16 + q * 4;
            float4 bb = *reinterpret_cast<const float4*>(&bias[col]);
            uint2 w = { pk2(acc[i][jn][0] + bb.x * bsc, acc[i][jn][1] + bb.y * bsc),
                        pk2(acc[i][jn][2] + bb.z * bsc, acc[i][jn][3] + bb.w * bsc) };
            *reinterpret_cast<uint2*>(&C[(size_t)row * N + col]) = w;
        }
}

// ---------------- V transpose per head: VT[nh][d][tau] ------------------
__global__ __launch_bounds__(256) void vtrans(const u16* __restrict__ V, u16* __restrict__ VT)
{
    __shared__ __align__(16) u16 tile[64 * 72];
    const int nh = blockIdx.y, t0 = blockIdx.x * 64;
    const u16* src = V + (size_t)nh * TS * DH;
    u16* dst = VT + (size_t)nh * DH * TS;
    const int t = threadIdx.x, r = t >> 2, c0 = (t & 3) << 4;
    *reinterpret_cast<uint4*>(&tile[r * 72 + c0]) =
        *reinterpret_cast<const uint4*>(&src[(size_t)(t0 + r) * DH + c0]);
    *reinterpret_cast<uint4*>(&tile[r * 72 + c0 + 8]) =
        *reinterpret_cast<const uint4*>(&src[(size_t)(t0 + r) * DH + c0 + 8]);
    __syncthreads();
    const int d = t >> 2, tc = (t & 3) << 4;
    u16 tmp[16];
#pragma unroll
    for (int j = 0; j < 16; ++j) tmp[j] = tile[(tc + j) * 72 + d];
    *reinterpret_cast<uint4*>(&dst[(size_t)d * TS + t0 + tc]) = *reinterpret_cast<const uint4*>(&tmp[0]);
    *reinterpret_cast<uint4*>(&dst[(size_t)d * TS + t0 + tc + 8]) = *reinterpret_cast<const uint4*>(&tmp[8]);
}

// -------- final GEMM: C[M,N](f32) = A[M,K](bf16) @ BT^T + bias ----------
__global__ __launch_bounds__(256) void gemm_out(
    const u16* __restrict__ A, const u16* __restrict__ BT,
    const float* __restrict__ bias, float* __restrict__ C,
    int M, int N, int K)
{
    __shared__ __align__(16) u16 As[64 * 32];
    __shared__ __align__(16) u16 Bs[128 * 32];
    const int m0 = blockIdx.y * 64, n0 = blockIdx.x * 128;
    const int tid = threadIdx.x, wid = tid >> 6, lane = tid & 63;
    const int q = lane >> 4, c = lane & 15;
    const int wm = wid >> 1, wn = wid & 1;
    const int arow = tid >> 2, acol = (tid & 3) << 3;
    const u16* ag = A + (size_t)(m0 + arow) * K + acol;
    const u16* bg0 = BT + (size_t)(n0 + arow) * K + acol;
    const u16* bg1 = BT + (size_t)(n0 + 64 + arow) * K + acol;
    f32x4 acc[2][4] = {};
    for (int k0 = 0; k0 < K; k0 += 32) {
        glds16(ag, &As[tid * 8]);
        glds16(bg0, &Bs[tid * 8]);
        glds16(bg1, &Bs[2048 + tid * 8]);
        ag += 32; bg0 += 32; bg1 += 32;
        __syncthreads();
        bf16x8 af[2], bf[4];
#pragma unroll
        for (int jm = 0; jm < 2; ++jm) af[jm] = ldb8(&As[(wm * 32 + jm * 16 + c) * 32 + q * 8]);
#pragma unroll
        for (int jn = 0; jn < 4; ++jn) bf[jn] = ldb8(&Bs[(wn * 64 + jn * 16 + c) * 32 + q * 8]);
#pragma unroll
        for (int jm = 0; jm < 2; ++jm)
#pragma unroll
            for (int jn = 0; jn < 4; ++jn)
                acc[jm][jn] = MFMA16(bf[jn], af[jm], acc[jm][jn], 0, 0, 0);
        __syncthreads();
    }
#pragma unroll
    for (int jm = 0; jm < 2; ++jm)
#pragma unroll
        for (int jn = 0; jn < 4; ++jn) {
            int row = m0 + wm * 32 + jm * 16 + c;
            int col = n0 + wn * 64 + jn * 16 + q * 4;
            float4 bb = *reinterpret_cast<const float4*>(&bias[col]);
            float4 v = { acc[jm][jn][0] + bb.x, acc[jm][jn][1] + bb.y,
                         acc[jm][jn][2] + bb.z, acc[jm][jn][3] + bb.w };
            *reinterpret_cast<float4*>(&C[(size_t)row * N + col]) = v;
        }
}

// -------- pass 1: Zf = 1/sum_h exp2(S'), frag-row layout ----------------
// grid (32 sb, 16 tb, 2 n); t-tile 128, Q+K staged via glds.
// Zf[((n*32+sb)*2048 + t)*64 + q*16 + i*4 + r], s = sb*64 + i*16 + q*4 + r
__global__ __launch_bounds__(256) void z_kernel(
    const u16* __restrict__ Qp, const u16* __restrict__ Kp, u16* __restrict__ Zf)
{
    __shared__ __align__(16) u16 Ks[64 * 64];
    __shared__ __align__(16) u16 Qs[128 * 64];
    const int sb = blockIdx.x, tb = blockIdx.y, n = blockIdx.z;
    const int s0 = sb * 64, t0 = tb * 128;
    const int tid = threadIdx.x, wid = tid >> 6, lane = tid & 63;
    const int q = lane >> 4, c = lane & 15;
    const int krow = tid >> 3, kch = tid & 7;
    const int xsw = (kch ^ (krow & 7)) << 3;
    const u16* kg0 = Kp + (size_t)(n * NH) * TS * DH + (size_t)(s0 + krow) * DH + xsw;
    const u16* qg0 = Qp + (size_t)(n * NH) * TS * DH + (size_t)(t0 + krow) * DH + xsw;
    float zacc[2][4][4] = {};
    for (int h = 0; h < NH; ++h) {
        glds16(kg0, &Ks[tid * 8]);
        glds16(kg0 + (size_t)32 * DH, &Ks[2048 + tid * 8]);
#pragma unroll
        for (int L = 0; L < 4; ++L)
            glds16(qg0 + (size_t)(L * 32) * DH, &Qs[L * 2048 + tid * 8]);
        kg0 += (size_t)TS * DH; qg0 += (size_t)TS * DH;
        __syncthreads();
        bf16x8 qa[2][2], kb[4][2];
#pragma unroll
        for (int jm = 0; jm < 2; ++jm)
#pragma unroll
            for (int kf = 0; kf < 2; ++kf)
                qa[jm][kf] = ldb8(&Qs[(wid * 32 + jm * 16 + c) * 64 + (((kf * 4 + q) ^ (c & 7)) << 3)]);
#pragma unroll
        for (int i = 0; i < 4; ++i)
#pragma unroll
            for (int kf = 0; kf < 2; ++kf)
                kb[i][kf] = ldb8(&Ks[(i * 16 + c) * 64 + (((kf * 4 + q) ^ (c & 7)) << 3)]);
        f32x4 s_[2][4] = {};
#pragma unroll
        for (int kf = 0; kf < 2; ++kf)
#pragma unroll
            for (int jm = 0; jm < 2; ++jm)
#pragma unroll
                for (int i = 0; i < 4; ++i)
                    s_[jm][i] = MFMA16(kb[i][kf], qa[jm][kf], s_[jm][i], 0, 0, 0);
#pragma unroll
        for (int jm = 0; jm < 2; ++jm)
#pragma unroll
            for (int i = 0; i < 4; ++i)
#pragma unroll
                for (int r = 0; r < 4; ++r)
                    zacc[jm][i][r] += fexp2(s_[jm][i][r]);
        __syncthreads();
    }
#pragma unroll
    for (int jm = 0; jm < 2; ++jm) {
        int t = t0 + wid * 32 + jm * 16 + c;
        size_t zb = ((size_t)((n * 32 + sb) * 2048) + t) * 64 + q * 16;
        unsigned w32[8];
#pragma unroll
        for (int i = 0; i < 4; ++i) {
            w32[i * 2 + 0] = pk2(1.0f / zacc[jm][i][0], 1.0f / zacc[jm][i][1]);
            w32[i * 2 + 1] = pk2(1.0f / zacc[jm][i][2], 1.0f / zacc[jm][i][3]);
        }
        *reinterpret_cast<uint4*>(&Zf[zb])     = *reinterpret_cast<const uint4*>(&w32[0]);
        *reinterpret_cast<uint4*>(&Zf[zb + 8]) = *reinterpret_cast<const uint4*>(&w32[4]);
    }
}

// -------- pass 2: out2[h] = (exp2(S') * Zinv) @ V[h] --------------------
// grid (32 tb, 16 h, 2 n); t-tile 64 (4 waves x 16t).
__global__ __launch_bounds__(256) void attn_kernel(
    const u16* __restrict__ Qp, const u16* __restrict__ Kp, const u16* __restrict__ VT,
    const u16* __restrict__ Zf, u16* __restrict__ o2)
{
    __shared__ __align__(16) u16 Ks[64 * 64];
    __shared__ __align__(16) u16 Vs[64 * 64];
    __shared__ __align__(16) u16 Ps[64 * 72];   // [t][s], wave-private 16-row bands
    const int tb = blockIdx.x, h = blockIdx.y, n = blockIdx.z;
    const int t0 = tb * 64;
    const int tid = threadIdx.x, wid = tid >> 6, lane = tid & 63;
    const int q = lane >> 4, c = lane & 15;
    const int krow = tid >> 3, kch = tid & 7;
    const int xsw = (kch ^ (krow & 7)) << 3;
    const size_t base = (size_t)(n * NH + h) * TS * DH;
    const u16* Qh = Qp + base;
    const int tme = t0 + wid * 16 + c;          // this lane's t row
    bf16x8 qa[2];
#pragma unroll
    for (int kf = 0; kf < 2; ++kf)
        qa[kf] = ldb8(&Qh[(size_t)tme * DH + kf * 32 + q * 8]);
    // strength-reduced streaming pointers
    const u16* kg0 = Kp + base + (size_t)krow * DH + xsw;
    const u16* kg1 = kg0 + (size_t)32 * DH;
    const u16* vg0 = VT + base + (size_t)krow * TS + xsw;
    const u16* vg1 = vg0 + (size_t)32 * TS;
    const u16* zg  = Zf + ((size_t)(n * 32) * 2048 + tme) * 64 + q * 16;
    f32x4 oacc[4] = {};
    for (int sb = 0; sb < 32; ++sb) {
        glds16(kg0, &Ks[tid * 8]);
        glds16(kg1, &Ks[2048 + tid * 8]);
        glds16(vg0, &Vs[tid * 8]);
        glds16(vg1, &Vs[2048 + tid * 8]);
        u16 zl[16];
        *reinterpret_cast<uint4*>(&zl[0]) = *reinterpret_cast<const uint4*>(zg);
        *reinterpret_cast<uint4*>(&zl[8]) = *reinterpret_cast<const uint4*>(zg + 8);
        kg0 += 64 * DH; kg1 += 64 * DH; vg0 += 64; vg1 += 64; zg += (size_t)2048 * 64;
        __syncthreads();
        bf16x8 kb[4][2];
#pragma unroll
        for (int i = 0; i < 4; ++i)
#pragma unroll
            for (int kf = 0; kf < 2; ++kf)
                kb[i][kf] = ldb8(&Ks[(i * 16 + c) * 64 + (((kf * 4 + q) ^ (c & 7)) << 3)]);
        f32x4 s_[4] = {};
#pragma unroll
        for (int kf = 0; kf < 2; ++kf)
#pragma unroll
            for (int i = 0; i < 4; ++i)
                s_[i] = MFMA16(kb[i][kf], qa[kf], s_[i], 0, 0, 0);
#pragma unroll
        for (int i = 0; i < 4; ++i) {
            float p0 = fexp2(s_[i][0]) * bf2f(zl[i * 4 + 0]);
            float p1 = fexp2(s_[i][1]) * bf2f(zl[i * 4 + 1]);
            float p2 = fexp2(s_[i][2]) * bf2f(zl[i * 4 + 2]);
            float p3 = fexp2(s_[i][3]) * bf2f(zl[i * 4 + 3]);
            uint2 w = { pk2(p0, p1), pk2(p2, p3) };
            *reinterpret_cast<uint2*>(&Ps[(wid * 16 + c) * 72 + i * 16 + q * 4]) = w;
        }
        bf16x8 pa[2], vb[4][2];
#pragma unroll
        for (int kf = 0; kf < 2; ++kf)
            pa[kf] = ldb8(&Ps[(wid * 16 + c) * 72 + kf * 32 + q * 8]);
#pragma unroll
        for (int dn = 0; dn < 4; ++dn)
#pragma unroll
            for (int kf = 0; kf < 2; ++kf)
                vb[dn][kf] = ldb8(&Vs[(dn * 16 + c) * 64 + (((kf * 4 + q) ^ (c & 7)) << 3)]);
#pragma unroll
        for (int kf = 0; kf < 2; ++kf)
#pragma unroll
            for (int dn = 0; dn < 4; ++dn)
                oacc[dn] = MFMA16(vb[dn][kf], pa[kf], oacc[dn], 0, 0, 0);
        __syncthreads();
    }
#pragma unroll
    for (int dn = 0; dn < 4; ++dn) {
        uint2 w = { pk2(oacc[dn][0], oacc[dn][1]), pk2(oacc[dn][2], oacc[dn][3]) };
        *reinterpret_cast<uint2*>(&o2[base + (size_t)tme * DH + dn * 16 + q * 4]) = w;
    }
}

extern "C" void kernel_launch(void* const* d_in, const int* in_sizes, int n_in,
                              void* d_out, int out_size, void* d_ws, size_t ws_size,
                              hipStream_t stream)
{
    const float* q  = (const float*)d_in[0];
    const float* k  = (const float*)d_in[1];
    const float* v  = (const float*)d_in[2];
    const float* Wq = (const float*)d_in[3];
    const float* bq = (const float*)d_in[4];
    const float* Wk = (const float*)d_in[5];
    const float* bk = (const float*)d_in[6];
    const float* Wv = (const float*)d_in[7];
    const float* bv = (const float*)d_in[8];
    const float* Wo = (const float*)d_in[9];
    const float* bo = (const float*)d_in[10];
    float* out = (float*)d_out;

    // ws (u16 elems), 56 MiB: wT x4 (2 MiB) + S1..S6 (8 MiB each)
    //   qb=S1 kb=S2 vb=S3 (live through gemm_qkv)  Qp=S4 Kp=S5 Vp=S6
    //   VTb=S1 (qb dead)  Zf=S2..S3 (16 MiB, kb/vb dead)  o2=S6 (Vp dead)
    u16* ws  = (u16*)d_ws;
    u16* wqT = ws + 0 * 1048576;
    u16* wkT = ws + 1 * 1048576;
    u16* wvT = ws + 2 * 1048576;
    u16* woT = ws + 3 * 1048576;
    u16* S1  = ws + 4194304;
    u16* S2  = S1 + 4194304;
    u16* S3  = S2 + 4194304;
    u16* S4  = S3 + 4194304;
    u16* S5  = S4 + 4194304;
    u16* S6  = S5 + 4194304;
    u16 *qb = S1, *kb = S2, *vb = S3;
    u16 *Qp = S4, *Kp = S5, *Vp = S6;
    u16 *VTb = S1, *Zf = S2, *o2 = S6;

    to_bf16<<<dim3(2048, 3), 256, 0, stream>>>(q, k, v, qb, kb, vb);
    wtrans<<<dim3(16, 16, 4), 256, 0, stream>>>(Wq, Wk, Wv, Wo, wqT, wkT, wvT, woT);
    gemm_qkv<<<dim3(8, 32, 3), 256, 0, stream>>>(qb, kb, vb, wqT, wkT, wvT,
                                                 bq, bk, bv, Qp, Kp, Vp);
    vtrans<<<dim3(32, 32), 256, 0, stream>>>(Vp, VTb);
    z_kernel<<<dim3(32, 16, 2), 256, 0, stream>>>(Qp, Kp, Zf);
    attn_kernel<<<dim3(32, 16, 2), 256, 0, stream>>>(Qp, Kp, VTb, Zf, o2);
    gemm_out<<<dim3(8, 64), 256, 0, stream>>>(o2, woT, bo, out, NB * TS, HD, HD);
}